// Round 1
// baseline (341.404 us; speedup 1.0000x reference)
//
#include <hip/hip_runtime.h>

typedef __bf16 bf16;
typedef __bf16 v8bf __attribute__((ext_vector_type(8)));
typedef __bf16 v4bf __attribute__((ext_vector_type(4)));
typedef float  v4f  __attribute__((ext_vector_type(4)));

__device__ __forceinline__ void gload_lds16(const void* g, void* l) {
    __builtin_amdgcn_global_load_lds(
        (const __attribute__((address_space(1))) void*)g,
        (__attribute__((address_space(3))) void*)l, 16, 0, 0);
}

// ---------------------------------------------------------------------------
// Kernel 1: LayerNorm over D=768 + bf16 casts. One block per row, 256 thr.
// Blocks 0..63 also zero the softmax row-sum accumulator L (16384 floats).
// ---------------------------------------------------------------------------
__global__ __launch_bounds__(256)
void ln_cast(const float* __restrict__ x, const float* __restrict__ g,
             const float* __restrict__ b, bf16* __restrict__ xn,
             bf16* __restrict__ xv, float* __restrict__ L)
{
    const long row = blockIdx.x;
    const float* xr = x + row * 768;
    const int tid = threadIdx.x;
    const int wave = tid >> 6, lane = tid & 63;

    if (row < 64) L[row * 256 + tid] = 0.0f;

    float a0 = xr[tid], a1 = xr[tid + 256], a2 = xr[tid + 512];
    float s = a0 + a1 + a2;
    #pragma unroll
    for (int off = 32; off; off >>= 1) s += __shfl_xor(s, off);
    __shared__ float sh[4], sh2[4];
    if (!lane) sh[wave] = s;
    __syncthreads();
    const float mu = (sh[0] + sh[1] + sh[2] + sh[3]) * (1.0f / 768.0f);

    float d0 = a0 - mu, d1 = a1 - mu, d2 = a2 - mu;
    float ss = d0 * d0 + d1 * d1 + d2 * d2;
    #pragma unroll
    for (int off = 32; off; off >>= 1) ss += __shfl_xor(ss, off);
    if (!lane) sh2[wave] = ss;
    __syncthreads();
    const float var = (sh2[0] + sh2[1] + sh2[2] + sh2[3]) * (1.0f / 768.0f);
    const float rstd = rsqrtf(var + 1e-5f);

    bf16* xnr = xn + row * 768;
    bf16* xvr = xv + row * 768;
    xnr[tid]       = (bf16)(d0 * rstd * g[tid]       + b[tid]);
    xnr[tid + 256] = (bf16)(d1 * rstd * g[tid + 256] + b[tid + 256]);
    xnr[tid + 512] = (bf16)(d2 * rstd * g[tid + 512] + b[tid + 512]);
    xvr[tid]       = (bf16)a0;
    xvr[tid + 256] = (bf16)a1;
    xvr[tid + 512] = (bf16)a2;
}

// ---------------------------------------------------------------------------
// Kernel 2: weight fp32 -> bf16 convert into Wcat halves. grid (576,2).
// ---------------------------------------------------------------------------
__global__ __launch_bounds__(256)
void cvt_w(const float* __restrict__ Wq, const float* __restrict__ Wk,
           bf16* __restrict__ Wcat)
{
    const int z = blockIdx.y;
    const float* src = z ? Wk : Wq;
    bf16* dst = Wcat + (long)z * 768 * 768;
    const int i = (blockIdx.x * 256 + threadIdx.x) * 4;
    const float4 v = *(const float4*)(src + i);
    v4bf o = {(bf16)v.x, (bf16)v.y, (bf16)v.z, (bf16)v.w};
    *(v4bf*)(dst + i) = o;
}

// ---------------------------------------------------------------------------
// Kernel 2b: 64x64-tile bf16 transpose, XOR-swizzled LDS (conflict-free).
// in: [B][2048][768] -> outT: [B][768][2048]. grid (32, 12, 8), 256 thr.
// ---------------------------------------------------------------------------
__global__ __launch_bounds__(256)
void transpose_bf(const bf16* __restrict__ in, bf16* __restrict__ outT)
{
    __shared__ __attribute__((aligned(16))) bf16 tile[64 * 64];
    const int t0 = blockIdx.x * 64, d0 = blockIdx.y * 64;
    in   += (long)blockIdx.z * 2048 * 768;
    outT += (long)blockIdx.z * 768 * 2048;
    const int tid = threadIdx.x;

    #pragma unroll
    for (int it = 0; it < 2; ++it) {
        const int lin = it * 256 + tid;
        const int r = lin >> 3;
        const int g = lin & 7;
        const int pg = g ^ (r & 7) ^ ((r >> 3) & 7);
        v8bf v = *(const v8bf*)(in + (long)(t0 + r) * 768 + d0 + g * 8);
        *(v8bf*)(tile + r * 64 + pg * 8) = v;
    }
    __syncthreads();
    #pragma unroll
    for (int it = 0; it < 2; ++it) {
        const int lin = it * 256 + tid;
        const int dd = lin >> 3;
        const int tb = lin & 7;
        v8bf o;
        #pragma unroll
        for (int j = 0; j < 8; ++j) {
            const int t = tb * 8 + j;
            const int pg = (dd >> 3) ^ (t & 7) ^ ((t >> 3) & 7);
            o[j] = tile[t * 64 + pg * 8 + (dd & 7)];
        }
        *(v8bf*)(outT + (long)(d0 + dd) * 2048 + t0 + tb * 8) = o;
    }
}

// ---------------------------------------------------------------------------
// Kernel 3: merged Q/K projection. A=xn [16384,768], W=[1536,768] (Wq;Wk).
// 128x128 tile, BK=64 dual-panel m97 staging. grid 1536 1-D, XCD swizzle.
// ---------------------------------------------------------------------------
__global__ __launch_bounds__(256)
void gemm_qk(const bf16* __restrict__ A, const bf16* __restrict__ W,
             const float* __restrict__ bq, const float* __restrict__ bk,
             float qscale, bf16* __restrict__ Qb, bf16* __restrict__ Kb)
{
    __shared__ __attribute__((aligned(16))) bf16 As[2][128 * 32];
    __shared__ __attribute__((aligned(16))) bf16 Bs[2][128 * 32];

    const int bx = blockIdx.x;
    const int r = bx & 7, j = bx >> 3;
    const int m0 = (r * 16 + j / 12) * 128;
    const int n0 = (j % 12) * 128;

    const int tid = threadIdx.x, wave = tid >> 6, lane = tid & 63;
    const bf16* Ab = A + (long)m0 * 768;
    const bf16* Bb = W + (long)n0 * 768;

    const int lrow = lane >> 2;
    const int lk   = (lane & 3) * 8;
    const int wm = (wave >> 1) * 64, wn = (wave & 1) * 64;
    const int lr = lane & 15, lq = lane >> 4;

    v4f acc[4][4] = {};

    for (int kk = 0; kk < 768; kk += 64) {
        #pragma unroll
        for (int p = 0; p < 2; ++p)
            #pragma unroll
            for (int it = 0; it < 2; ++it) {
                const int c = it * 4 + wave;
                const int row = c * 16 + lrow;
                gload_lds16(Ab + (long)row * 768 + kk + p * 32 + lk,
                            (char*)As[p] + c * 1024);
                gload_lds16(Bb + (long)row * 768 + kk + p * 32 + lk,
                            (char*)Bs[p] + c * 1024);
            }
        __syncthreads();

        #pragma unroll
        for (int p = 0; p < 2; ++p) {
            v8bf af[4], bfr[4];
            #pragma unroll
            for (int i = 0; i < 4; ++i)
                af[i] = *(const v8bf*)(As[p] + (wm + i * 16 + lr) * 32 + lq * 8);
            #pragma unroll
            for (int jj = 0; jj < 4; ++jj)
                bfr[jj] = *(const v8bf*)(Bs[p] + (wn + jj * 16 + lr) * 32 + lq * 8);
            #pragma unroll
            for (int i = 0; i < 4; ++i)
                #pragma unroll
                for (int jj = 0; jj < 4; ++jj)
                    acc[i][jj] = __builtin_amdgcn_mfma_f32_16x16x32_bf16(
                        af[i], bfr[jj], acc[i][jj], 0, 0, 0);
        }
        __syncthreads();
    }

    const bool isQ = (n0 < 768);
    const float* bias = isQ ? bq : bk;
    const float sc = isQ ? qscale : 1.0f;
    bf16* C = isQ ? Qb : Kb;
    const int c0 = isQ ? n0 : n0 - 768;

    #pragma unroll
    for (int i = 0; i < 4; ++i) {
        #pragma unroll
        for (int rr = 0; rr < 4; ++rr) {
            const int row = m0 + wm + i * 16 + lq * 4 + rr;
            #pragma unroll
            for (int jj = 0; jj < 4; ++jj) {
                const int col = c0 + wn + jj * 16 + lr;
                C[(long)row * 768 + col] = (bf16)((acc[i][jj][rr] + bias[col]) * sc);
            }
        }
    }
}

// ---------------------------------------------------------------------------
// Kernel 4: E = exp(Q.K^T) (scale in Q) + row-sum atomics into L.
// NEW: 128(M)x256(N) tile, BK=64, 8 waves (512 thr), 3-slot LDS ring,
// counted vmcnt(6) prefetch pipeline (T3+T4), XOR chunk swizzle on both the
// pre-swizzled global_load_lds source and the ds_read address (T2, rule 21),
// setprio around MFMA clusters (T5). 2 sub-phases per K-tile, A-frags held
// in registers across both. Hazard-free by construction:
//   - slot (t+2)%3 re-staged at iter t was last READ at iter t-1, and all
//     waves passed lgkmcnt(0)+barrier before iter t issues stages (no WAR).
//   - vmcnt(6) at end of iter t completes exactly tile t+1's 6 loads/wave
//     (outstanding = 6 of t+1 + 6 of t+2); barrier makes it block-wide (RAW).
// grid 1024 1-D: batch = bx&7 (XCD), j=bx>>3: mt=j>>3, nt=j&7.
// ---------------------------------------------------------------------------
__global__ __launch_bounds__(512, 2)
void gemm_scores(const bf16* __restrict__ Q, const bf16* __restrict__ K,
                 bf16* __restrict__ E, float* __restrict__ L)
{
    // slot = A[128][64] (16 KB) + B[256][64] (32 KB) = 48 KB; 3 slots = 144 KB
    __shared__ __attribute__((aligned(16))) bf16 lds[3][24576];

    const int bx = blockIdx.x;
    const int batch = bx & 7, j = bx >> 3;      // j in [0,128)
    const int mt = j >> 3, nt = j & 7;
    const int m0 = mt * 128, n0 = nt * 256;

    const bf16* Ag = Q + (long)batch * 2048 * 768 + (long)m0 * 768;
    const bf16* Bg = K + (long)batch * 2048 * 768 + (long)n0 * 768;
    bf16* C = E + (long)batch * 2048 * 2048;
    float* Lb = L + (long)batch * 2048;

    const int tid = threadIdx.x, wv = tid >> 6, lane = tid & 63;
    const int wr = wv >> 2, wc = wv & 3;        // wave = 64(M) x 64(N)
    const int lr = lane & 15, lq = lane >> 4;

    // stage one 1 KB chunk-instr: linear LDS dest, XOR-pre-swizzled source.
    // lin = a*64+lane; r = lin>>3 (row, 128 B/row); phys chunk = lin&7;
    // logical chunk in source = (lin&7) ^ (r&7).
    auto stageA = [&](int slot, int kk, int a) {
        const int lin = a * 64 + lane;
        const int r = lin >> 3;
        const int ck = (lin & 7) ^ (r & 7);
        gload_lds16(Ag + (long)r * 768 + kk + ck * 8,
                    (char*)lds[slot] + a * 1024);
    };
    auto stageB = [&](int slot, int kk, int b) {
        const int lin = b * 64 + lane;
        const int r = lin >> 3;
        const int ck = (lin & 7) ^ (r & 7);
        gload_lds16(Bg + (long)r * 768 + kk + ck * 8,
                    (char*)lds[slot] + 16384 + b * 1024);
    };

    v4f acc[4][4] = {};
    const int NT = 12;  // 768 / 64

    // prologue: stage tiles 0 and 1 (6 instrs/wave each)
    #pragma unroll
    for (int tt = 0; tt < 2; ++tt) {
        stageA(tt, tt * 64, wv * 2 + 0);
        stageA(tt, tt * 64, wv * 2 + 1);
        #pragma unroll
        for (int l = 0; l < 4; ++l) stageB(tt, tt * 64, wv * 4 + l);
    }
    asm volatile("s_waitcnt vmcnt(6)" ::: "memory");  // tile 0 landed
    __builtin_amdgcn_s_barrier();

    for (int t = 0; t < NT; ++t) {
        const int cur = t % 3;
        const int nxt = (t + 2) % 3;
        const int kk2 = (t + 2) * 64;
        const bf16* As = lds[cur];
        const bf16* Bs = lds[cur] + 8192;       // +16 KB
        const bool pre = (t + 2 < NT);

        // ---- sub-phase 0: read A (all) + B cols 0..127; MFMA j=0,1 ----
        v8bf af[4][2], bfr[2][2];
        #pragma unroll
        for (int i = 0; i < 4; ++i) {
            const int row = wr * 64 + i * 16 + lr;
            #pragma unroll
            for (int s = 0; s < 2; ++s)
                af[i][s] = *(const v8bf*)(As + row * 64 +
                                          (((s * 4 + lq) ^ (row & 7)) << 3));
        }
        #pragma unroll
        for (int jn = 0; jn < 2; ++jn) {
            const int row = wc * 64 + jn * 16 + lr;
            #pragma unroll
            for (int s = 0; s < 2; ++s)
                bfr[jn][s] = *(const v8bf*)(Bs + row * 64 +
                                            (((s * 4 + lq) ^ (row & 7)) << 3));
        }
        if (pre) {
            stageA(nxt, kk2, wv * 2 + 0);
            stageA(nxt, kk2, wv * 2 + 1);
            stageB(nxt, kk2, wv * 4 + 0);
        }
        __builtin_amdgcn_s_barrier();
        asm volatile("s_waitcnt lgkmcnt(0)" ::: "memory");
        __builtin_amdgcn_s_setprio(1);
        #pragma unroll
        for (int s = 0; s < 2; ++s)
            #pragma unroll
            for (int i = 0; i < 4; ++i)
                #pragma unroll
                for (int jn = 0; jn < 2; ++jn)
                    acc[i][jn] = __builtin_amdgcn_mfma_f32_16x16x32_bf16(
                        af[i][s], bfr[jn][s], acc[i][jn], 0, 0, 0);
        __builtin_amdgcn_s_setprio(0);
        __builtin_amdgcn_s_barrier();

        // ---- sub-phase 1: read B cols 128..255; MFMA j=2,3 ----
        #pragma unroll
        for (int jn = 0; jn < 2; ++jn) {
            const int row = wc * 64 + (jn + 2) * 16 + lr;
            #pragma unroll
            for (int s = 0; s < 2; ++s)
                bfr[jn][s] = *(const v8bf*)(Bs + row * 64 +
                                            (((s * 4 + lq) ^ (row & 7)) << 3));
        }
        if (pre) {
            stageB(nxt, kk2, wv * 4 + 1);
            stageB(nxt, kk2, wv * 4 + 2);
            stageB(nxt, kk2, wv * 4 + 3);
        }
        __builtin_amdgcn_s_barrier();
        asm volatile("s_waitcnt lgkmcnt(0)" ::: "memory");
        __builtin_amdgcn_s_setprio(1);
        #pragma unroll
        for (int s = 0; s < 2; ++s)
            #pragma unroll
            for (int i = 0; i < 4; ++i)
                #pragma unroll
                for (int jn = 0; jn < 2; ++jn)
                    acc[i][jn + 2] = __builtin_amdgcn_mfma_f32_16x16x32_bf16(
                        af[i][s], bfr[jn][s], acc[i][jn + 2], 0, 0, 0);
        __builtin_amdgcn_s_setprio(0);
        if (t < NT - 2)       asm volatile("s_waitcnt vmcnt(6)" ::: "memory");
        else if (t == NT - 2) asm volatile("s_waitcnt vmcnt(0)" ::: "memory");
        __builtin_amdgcn_s_barrier();
    }

    // epilogue: exp + 16-lane row-sum reduce + atomics + bf16 store
    #pragma unroll
    for (int i = 0; i < 4; ++i) {
        #pragma unroll
        for (int rr = 0; rr < 4; ++rr) {
            const int row = m0 + wr * 64 + i * 16 + lq * 4 + rr;
            float e[4], rs = 0.f;
            #pragma unroll
            for (int jn = 0; jn < 4; ++jn) {
                e[jn] = __expf(acc[i][jn][rr]);
                rs += e[jn];
            }
            #pragma unroll
            for (int off = 1; off < 16; off <<= 1) rs += __shfl_xor(rs, off);
            if (lr == 0) atomicAdd(&Lb[row], rs);
            #pragma unroll
            for (int jn = 0; jn < 4; ++jn) {
                const int col = n0 + wc * 64 + jn * 16 + lr;
                C[(long)row * 2048 + col] = (bf16)e[jn];
            }
        }
    }
}

// ---------------------------------------------------------------------------
// Kernel 5: Out = (E.V^T)/L + Xres (fp32). 64x128 (MxN) tile, K=2048, BK=64.
// grid 1536 1-D, XCD swizzle: batch=id&7, j=id>>3: m_tile=j/6, n_tile=j%6.
// LDS 24 KB, VGPR ~60 -> high occupancy (R4 config: best measured for pv).
// ---------------------------------------------------------------------------
__global__ __launch_bounds__(256)
void gemm_pv(const bf16* __restrict__ P, const bf16* __restrict__ VT,
             const float* __restrict__ L, const float* __restrict__ Xres,
             float* __restrict__ Out)
{
    __shared__ __attribute__((aligned(16))) bf16 As[2][64 * 32];
    __shared__ __attribute__((aligned(16))) bf16 Bs[2][128 * 32];

    const int bx = blockIdx.x;
    const int batch = bx & 7, j = bx >> 3;   // j in [0,192)
    const int m0 = (j / 6) * 64;             // 0..1984
    const int n0 = (j % 6) * 128;            // 0..640

    const bf16* Ab = P  + (long)batch * 2048 * 2048 + (long)m0 * 2048;
    const bf16* Bb = VT + (long)batch * 768 * 2048  + (long)n0 * 2048;
    const float* Lb = L + (long)batch * 2048;
    const float* Xr = Xres + (long)batch * 2048 * 768;
    float* O = Out + (long)batch * 2048 * 768;

    const int tid = threadIdx.x, wave = tid >> 6, lane = tid & 63;
    const int lrow = lane >> 2;
    const int lk   = (lane & 3) * 8;
    const int wm = (wave >> 1) * 32, wn = (wave & 1) * 64;
    const int lr = lane & 15, lq = lane >> 4;

    v4f acc[2][4] = {};

    for (int kk = 0; kk < 2048; kk += 64) {
        #pragma unroll
        for (int p = 0; p < 2; ++p) {
            gload_lds16(Ab + (long)(wave * 16 + lrow) * 2048 + kk + p * 32 + lk,
                        (char*)As[p] + wave * 1024);
            #pragma unroll
            for (int it = 0; it < 2; ++it) {
                const int c = it * 4 + wave;
                gload_lds16(Bb + (long)(c * 16 + lrow) * 2048 + kk + p * 32 + lk,
                            (char*)Bs[p] + c * 1024);
            }
        }
        __syncthreads();

        #pragma unroll
        for (int p = 0; p < 2; ++p) {
            v8bf af[2], bfr[4];
            #pragma unroll
            for (int i = 0; i < 2; ++i)
                af[i] = *(const v8bf*)(As[p] + (wm + i * 16 + lr) * 32 + lq * 8);
            #pragma unroll
            for (int jj = 0; jj < 4; ++jj)
                bfr[jj] = *(const v8bf*)(Bs[p] + (wn + jj * 16 + lr) * 32 + lq * 8);
            #pragma unroll
            for (int i = 0; i < 2; ++i)
                #pragma unroll
                for (int jj = 0; jj < 4; ++jj)
                    acc[i][jj] = __builtin_amdgcn_mfma_f32_16x16x32_bf16(
                        af[i], bfr[jj], acc[i][jj], 0, 0, 0);
        }
        __syncthreads();
    }

    #pragma unroll
    for (int i = 0; i < 2; ++i) {
        #pragma unroll
        for (int rr = 0; rr < 4; ++rr) {
            const int row = m0 + wm + i * 16 + lq * 4 + rr;
            const float invL = 1.0f / Lb[row];
            #pragma unroll
            for (int jj = 0; jj < 4; ++jj) {
                const int col = n0 + wn + jj * 16 + lr;
                const long idx = (long)row * 768 + col;
                O[idx] = acc[i][jj][rr] * invL + Xr[idx];
            }
        }
    }
}

// ---------------------------------------------------------------------------
extern "C" void kernel_launch(void* const* d_in, const int* in_sizes, int n_in,
                              void* d_out, int out_size, void* d_ws, size_t ws_size,
                              hipStream_t stream)
{
    const float* x    = (const float*)d_in[0];
    const float* ln_g = (const float*)d_in[1];
    const float* ln_b = (const float*)d_in[2];
    const float* Wq   = (const float*)d_in[3];
    const float* bq   = (const float*)d_in[4];
    const float* Wk   = (const float*)d_in[5];
    const float* bk   = (const float*)d_in[6];
    float* out = (float*)d_out;

    const long R = 8L * 2048;  // 16384 rows
    char* ws = (char*)d_ws;
    size_t off = 0;
    auto take = [&](size_t bytes) -> char* {
        char* p = ws + off;
        off += (bytes + 255) & ~(size_t)255;
        return p;
    };
    bf16*  xn   = (bf16*)take(R * 768 * 2);   // reused as xvT after projection
    bf16*  xv   = (bf16*)take(R * 768 * 2);
    bf16*  Qb   = (bf16*)take(R * 768 * 2);
    bf16*  Kb   = (bf16*)take(R * 768 * 2);
    bf16*  Wcat = (bf16*)take(1536L * 768 * 2);
    float* Lrow = (float*)take(R * 4);        // softmax denominators
    bf16*  Sc   = (bf16*)take(8L * 2048 * 2048 * 2);  // E = exp(scores)

    ln_cast<<<R, 256, 0, stream>>>(x, ln_g, ln_b, xn, xv, Lrow);
    cvt_w<<<dim3(576, 2), 256, 0, stream>>>(Wq, Wk, Wcat);

    const float qscale = 0.036084391824351615f;  // 1/sqrt(768), folded into Q
    gemm_qk<<<1536, 256, 0, stream>>>(xn, Wcat, bq, bk, qscale, Qb, Kb);

    // xn dead now; reuse its buffer for xvT [8][768][2048]
    bf16* xvT = xn;
    transpose_bf<<<dim3(32, 12, 8), 256, 0, stream>>>(xv, xvT);

    gemm_scores<<<1024, 512, 0, stream>>>(Qb, Kb, Sc, Lrow);
    gemm_pv<<<1536, 256, 0, stream>>>(Sc, xvT, Lrow, x, out);
}

// Round 2
// 335.740 us; speedup vs baseline: 1.0169x; 1.0169x over previous
//
#include <hip/hip_runtime.h>

typedef __bf16 bf16;
typedef __bf16 v8bf __attribute__((ext_vector_type(8)));
typedef __bf16 v4bf __attribute__((ext_vector_type(4)));
typedef float  v4f  __attribute__((ext_vector_type(4)));

__device__ __forceinline__ void gload_lds16(const void* g, void* l) {
    __builtin_amdgcn_global_load_lds(
        (const __attribute__((address_space(1))) void*)g,
        (__attribute__((address_space(3))) void*)l, 16, 0, 0);
}

// ---------------------------------------------------------------------------
// Kernel 1: LayerNorm over D=768 + bf16 casts. One block per row, 256 thr.
// Blocks 0..63 also zero the softmax row-sum accumulator L (16384 floats).
// ---------------------------------------------------------------------------
__global__ __launch_bounds__(256)
void ln_cast(const float* __restrict__ x, const float* __restrict__ g,
             const float* __restrict__ b, bf16* __restrict__ xn,
             bf16* __restrict__ xv, float* __restrict__ L)
{
    const long row = blockIdx.x;
    const float* xr = x + row * 768;
    const int tid = threadIdx.x;
    const int wave = tid >> 6, lane = tid & 63;

    if (row < 64) L[row * 256 + tid] = 0.0f;

    float a0 = xr[tid], a1 = xr[tid + 256], a2 = xr[tid + 512];
    float s = a0 + a1 + a2;
    #pragma unroll
    for (int off = 32; off; off >>= 1) s += __shfl_xor(s, off);
    __shared__ float sh[4], sh2[4];
    if (!lane) sh[wave] = s;
    __syncthreads();
    const float mu = (sh[0] + sh[1] + sh[2] + sh[3]) * (1.0f / 768.0f);

    float d0 = a0 - mu, d1 = a1 - mu, d2 = a2 - mu;
    float ss = d0 * d0 + d1 * d1 + d2 * d2;
    #pragma unroll
    for (int off = 32; off; off >>= 1) ss += __shfl_xor(ss, off);
    if (!lane) sh2[wave] = ss;
    __syncthreads();
    const float var = (sh2[0] + sh2[1] + sh2[2] + sh2[3]) * (1.0f / 768.0f);
    const float rstd = rsqrtf(var + 1e-5f);

    bf16* xnr = xn + row * 768;
    bf16* xvr = xv + row * 768;
    xnr[tid]       = (bf16)(d0 * rstd * g[tid]       + b[tid]);
    xnr[tid + 256] = (bf16)(d1 * rstd * g[tid + 256] + b[tid + 256]);
    xnr[tid + 512] = (bf16)(d2 * rstd * g[tid + 512] + b[tid + 512]);
    xvr[tid]       = (bf16)a0;
    xvr[tid + 256] = (bf16)a1;
    xvr[tid + 512] = (bf16)a2;
}

// ---------------------------------------------------------------------------
// Kernel 2: weight fp32 -> bf16 convert into Wcat halves. grid (576,2).
// ---------------------------------------------------------------------------
__global__ __launch_bounds__(256)
void cvt_w(const float* __restrict__ Wq, const float* __restrict__ Wk,
           bf16* __restrict__ Wcat)
{
    const int z = blockIdx.y;
    const float* src = z ? Wk : Wq;
    bf16* dst = Wcat + (long)z * 768 * 768;
    const int i = (blockIdx.x * 256 + threadIdx.x) * 4;
    const float4 v = *(const float4*)(src + i);
    v4bf o = {(bf16)v.x, (bf16)v.y, (bf16)v.z, (bf16)v.w};
    *(v4bf*)(dst + i) = o;
}

// ---------------------------------------------------------------------------
// Kernel 2b: 64x64-tile bf16 transpose, XOR-swizzled LDS (conflict-free).
// in: [B][2048][768] -> outT: [B][768][2048]. grid (32, 12, 8), 256 thr.
// ---------------------------------------------------------------------------
__global__ __launch_bounds__(256)
void transpose_bf(const bf16* __restrict__ in, bf16* __restrict__ outT)
{
    __shared__ __attribute__((aligned(16))) bf16 tile[64 * 64];
    const int t0 = blockIdx.x * 64, d0 = blockIdx.y * 64;
    in   += (long)blockIdx.z * 2048 * 768;
    outT += (long)blockIdx.z * 768 * 2048;
    const int tid = threadIdx.x;

    #pragma unroll
    for (int it = 0; it < 2; ++it) {
        const int lin = it * 256 + tid;
        const int r = lin >> 3;
        const int g = lin & 7;
        const int pg = g ^ (r & 7) ^ ((r >> 3) & 7);
        v8bf v = *(const v8bf*)(in + (long)(t0 + r) * 768 + d0 + g * 8);
        *(v8bf*)(tile + r * 64 + pg * 8) = v;
    }
    __syncthreads();
    #pragma unroll
    for (int it = 0; it < 2; ++it) {
        const int lin = it * 256 + tid;
        const int dd = lin >> 3;
        const int tb = lin & 7;
        v8bf o;
        #pragma unroll
        for (int j = 0; j < 8; ++j) {
            const int t = tb * 8 + j;
            const int pg = (dd >> 3) ^ (t & 7) ^ ((t >> 3) & 7);
            o[j] = tile[t * 64 + pg * 8 + (dd & 7)];
        }
        *(v8bf*)(outT + (long)(d0 + dd) * 2048 + t0 + tb * 8) = o;
    }
}

// ---------------------------------------------------------------------------
// Kernel 3: merged Q/K projection. A=xn [16384,768], W=[1536,768] (Wq;Wk).
// 128x128 tile, BK=64 dual-panel m97 staging. grid 1536 1-D, XCD swizzle.
// ---------------------------------------------------------------------------
__global__ __launch_bounds__(256)
void gemm_qk(const bf16* __restrict__ A, const bf16* __restrict__ W,
             const float* __restrict__ bq, const float* __restrict__ bk,
             float qscale, bf16* __restrict__ Qb, bf16* __restrict__ Kb)
{
    __shared__ __attribute__((aligned(16))) bf16 As[2][128 * 32];
    __shared__ __attribute__((aligned(16))) bf16 Bs[2][128 * 32];

    const int bx = blockIdx.x;
    const int r = bx & 7, j = bx >> 3;
    const int m0 = (r * 16 + j / 12) * 128;
    const int n0 = (j % 12) * 128;

    const int tid = threadIdx.x, wave = tid >> 6, lane = tid & 63;
    const bf16* Ab = A + (long)m0 * 768;
    const bf16* Bb = W + (long)n0 * 768;

    const int lrow = lane >> 2;
    const int lk   = (lane & 3) * 8;
    const int wm = (wave >> 1) * 64, wn = (wave & 1) * 64;
    const int lr = lane & 15, lq = lane >> 4;

    v4f acc[4][4] = {};

    for (int kk = 0; kk < 768; kk += 64) {
        #pragma unroll
        for (int p = 0; p < 2; ++p)
            #pragma unroll
            for (int it = 0; it < 2; ++it) {
                const int c = it * 4 + wave;
                const int row = c * 16 + lrow;
                gload_lds16(Ab + (long)row * 768 + kk + p * 32 + lk,
                            (char*)As[p] + c * 1024);
                gload_lds16(Bb + (long)row * 768 + kk + p * 32 + lk,
                            (char*)Bs[p] + c * 1024);
            }
        __syncthreads();

        #pragma unroll
        for (int p = 0; p < 2; ++p) {
            v8bf af[4], bfr[4];
            #pragma unroll
            for (int i = 0; i < 4; ++i)
                af[i] = *(const v8bf*)(As[p] + (wm + i * 16 + lr) * 32 + lq * 8);
            #pragma unroll
            for (int jj = 0; jj < 4; ++jj)
                bfr[jj] = *(const v8bf*)(Bs[p] + (wn + jj * 16 + lr) * 32 + lq * 8);
            #pragma unroll
            for (int i = 0; i < 4; ++i)
                #pragma unroll
                for (int jj = 0; jj < 4; ++jj)
                    acc[i][jj] = __builtin_amdgcn_mfma_f32_16x16x32_bf16(
                        af[i], bfr[jj], acc[i][jj], 0, 0, 0);
        }
        __syncthreads();
    }

    const bool isQ = (n0 < 768);
    const float* bias = isQ ? bq : bk;
    const float sc = isQ ? qscale : 1.0f;
    bf16* C = isQ ? Qb : Kb;
    const int c0 = isQ ? n0 : n0 - 768;

    #pragma unroll
    for (int i = 0; i < 4; ++i) {
        #pragma unroll
        for (int rr = 0; rr < 4; ++rr) {
            const int row = m0 + wm + i * 16 + lq * 4 + rr;
            #pragma unroll
            for (int jj = 0; jj < 4; ++jj) {
                const int col = c0 + wn + jj * 16 + lr;
                C[(long)row * 768 + col] = (bf16)((acc[i][jj][rr] + bias[col]) * sc);
            }
        }
    }
}

// ---------------------------------------------------------------------------
// Kernel 4: E = exp(Q.K^T) (scale in Q) + row-sum atomics into L.
// 128(M)x256(N) tile, BK=64, 8 waves (512 thr), 3-slot LDS ring,
// counted vmcnt(6) prefetch pipeline (T3+T4), XOR chunk swizzle both-sides
// (T2, rule 21), setprio around MFMA clusters (T5).
// grid 1024 1-D: batch = bx&7 (XCD), j=bx>>3: mt=j>>3, nt=j&7.
// ---------------------------------------------------------------------------
__global__ __launch_bounds__(512, 2)
void gemm_scores(const bf16* __restrict__ Q, const bf16* __restrict__ K,
                 bf16* __restrict__ E, float* __restrict__ L)
{
    // slot = A[128][64] (16 KB) + B[256][64] (32 KB) = 48 KB; 3 slots = 144 KB
    __shared__ __attribute__((aligned(16))) bf16 lds[3][24576];

    const int bx = blockIdx.x;
    const int batch = bx & 7, j = bx >> 3;      // j in [0,128)
    const int mt = j >> 3, nt = j & 7;
    const int m0 = mt * 128, n0 = nt * 256;

    const bf16* Ag = Q + (long)batch * 2048 * 768 + (long)m0 * 768;
    const bf16* Bg = K + (long)batch * 2048 * 768 + (long)n0 * 768;
    bf16* C = E + (long)batch * 2048 * 2048;
    float* Lb = L + (long)batch * 2048;

    const int tid = threadIdx.x, wv = tid >> 6, lane = tid & 63;
    const int wr = wv >> 2, wc = wv & 3;        // wave = 64(M) x 64(N)
    const int lr = lane & 15, lq = lane >> 4;

    auto stageA = [&](int slot, int kk, int a) {
        const int lin = a * 64 + lane;
        const int r = lin >> 3;
        const int ck = (lin & 7) ^ (r & 7);
        gload_lds16(Ag + (long)r * 768 + kk + ck * 8,
                    (char*)lds[slot] + a * 1024);
    };
    auto stageB = [&](int slot, int kk, int b) {
        const int lin = b * 64 + lane;
        const int r = lin >> 3;
        const int ck = (lin & 7) ^ (r & 7);
        gload_lds16(Bg + (long)r * 768 + kk + ck * 8,
                    (char*)lds[slot] + 16384 + b * 1024);
    };

    v4f acc[4][4] = {};
    const int NT = 12;  // 768 / 64

    #pragma unroll
    for (int tt = 0; tt < 2; ++tt) {
        stageA(tt, tt * 64, wv * 2 + 0);
        stageA(tt, tt * 64, wv * 2 + 1);
        #pragma unroll
        for (int l = 0; l < 4; ++l) stageB(tt, tt * 64, wv * 4 + l);
    }
    asm volatile("s_waitcnt vmcnt(6)" ::: "memory");  // tile 0 landed
    __builtin_amdgcn_s_barrier();

    for (int t = 0; t < NT; ++t) {
        const int cur = t % 3;
        const int nxt = (t + 2) % 3;
        const int kk2 = (t + 2) * 64;
        const bf16* As = lds[cur];
        const bf16* Bs = lds[cur] + 8192;       // +16 KB
        const bool pre = (t + 2 < NT);

        // ---- sub-phase 0: read A (all) + B cols 0..127; MFMA j=0,1 ----
        v8bf af[4][2], bfr[2][2];
        #pragma unroll
        for (int i = 0; i < 4; ++i) {
            const int row = wr * 64 + i * 16 + lr;
            #pragma unroll
            for (int s = 0; s < 2; ++s)
                af[i][s] = *(const v8bf*)(As + row * 64 +
                                          (((s * 4 + lq) ^ (row & 7)) << 3));
        }
        #pragma unroll
        for (int jn = 0; jn < 2; ++jn) {
            const int row = wc * 64 + jn * 16 + lr;
            #pragma unroll
            for (int s = 0; s < 2; ++s)
                bfr[jn][s] = *(const v8bf*)(Bs + row * 64 +
                                            (((s * 4 + lq) ^ (row & 7)) << 3));
        }
        if (pre) {
            stageA(nxt, kk2, wv * 2 + 0);
            stageA(nxt, kk2, wv * 2 + 1);
            stageB(nxt, kk2, wv * 4 + 0);
        }
        __builtin_amdgcn_s_barrier();
        asm volatile("s_waitcnt lgkmcnt(0)" ::: "memory");
        __builtin_amdgcn_s_setprio(1);
        #pragma unroll
        for (int s = 0; s < 2; ++s)
            #pragma unroll
            for (int i = 0; i < 4; ++i)
                #pragma unroll
                for (int jn = 0; jn < 2; ++jn)
                    acc[i][jn] = __builtin_amdgcn_mfma_f32_16x16x32_bf16(
                        af[i][s], bfr[jn][s], acc[i][jn], 0, 0, 0);
        __builtin_amdgcn_s_setprio(0);
        __builtin_amdgcn_s_barrier();

        // ---- sub-phase 1: read B cols 128..255; MFMA j=2,3 ----
        #pragma unroll
        for (int jn = 0; jn < 2; ++jn) {
            const int row = wc * 64 + (jn + 2) * 16 + lr;
            #pragma unroll
            for (int s = 0; s < 2; ++s)
                bfr[jn][s] = *(const v8bf*)(Bs + row * 64 +
                                            (((s * 4 + lq) ^ (row & 7)) << 3));
        }
        if (pre) {
            stageB(nxt, kk2, wv * 4 + 1);
            stageB(nxt, kk2, wv * 4 + 2);
            stageB(nxt, kk2, wv * 4 + 3);
        }
        __builtin_amdgcn_s_barrier();
        asm volatile("s_waitcnt lgkmcnt(0)" ::: "memory");
        __builtin_amdgcn_s_setprio(1);
        #pragma unroll
        for (int s = 0; s < 2; ++s)
            #pragma unroll
            for (int i = 0; i < 4; ++i)
                #pragma unroll
                for (int jn = 0; jn < 2; ++jn)
                    acc[i][jn + 2] = __builtin_amdgcn_mfma_f32_16x16x32_bf16(
                        af[i][s], bfr[jn][s], acc[i][jn + 2], 0, 0, 0);
        __builtin_amdgcn_s_setprio(0);
        if (t < NT - 2)       asm volatile("s_waitcnt vmcnt(6)" ::: "memory");
        else if (t == NT - 2) asm volatile("s_waitcnt vmcnt(0)" ::: "memory");
        __builtin_amdgcn_s_barrier();
    }

    // epilogue: exp + 16-lane row-sum reduce + atomics + bf16 store
    #pragma unroll
    for (int i = 0; i < 4; ++i) {
        #pragma unroll
        for (int rr = 0; rr < 4; ++rr) {
            const int row = m0 + wr * 64 + i * 16 + lq * 4 + rr;
            float e[4], rs = 0.f;
            #pragma unroll
            for (int jn = 0; jn < 4; ++jn) {
                e[jn] = __expf(acc[i][jn][rr]);
                rs += e[jn];
            }
            #pragma unroll
            for (int off = 1; off < 16; off <<= 1) rs += __shfl_xor(rs, off);
            if (lr == 0) atomicAdd(&Lb[row], rs);
            #pragma unroll
            for (int jn = 0; jn < 4; ++jn) {
                const int col = n0 + wc * 64 + jn * 16 + lr;
                C[(long)row * 2048 + col] = (bf16)e[jn];
            }
        }
    }
}

// ---------------------------------------------------------------------------
// Kernel 5: Out = (E.V^T)/L + Xres (fp32).
// NEW: 128(M)x384(N) tile, BK=64, 8 waves (512 thr), ring-2 LDS double-buffer
// (2 x 64 KB), stage(t+1) issued at top of tile t, vmcnt(0) only at the tile
// boundary (~1.8K cy of MFMA cover the latency). XOR chunk swizzle both-sides
// (conflict-free ds_read_b128), setprio around each 24-MFMA cluster.
// Wave tile 64x96 -> 20 LDS reads / 48 MFMA per K-tile (LDS pipe ~69%).
// grid 256 1-D = 1 block/CU: batch = bx&7 (one batch per XCD -> VT panel
// 3 MB L2-resident), j=bx>>3: mt=j>>1 (16), nt=j&1 (2 x 384 cols).
// ---------------------------------------------------------------------------
__global__ __launch_bounds__(512, 2)
void gemm_pv(const bf16* __restrict__ P, const bf16* __restrict__ VT,
             const float* __restrict__ L, const float* __restrict__ Xres,
             float* __restrict__ Out)
{
    // slot = A[128][64] (16 KB) + B[384][64] (48 KB) = 64 KB; 2 slots = 128 KB
    __shared__ __attribute__((aligned(16))) bf16 lds[2][32768];

    const int bx = blockIdx.x;
    const int batch = bx & 7, j = bx >> 3;   // j in [0,32)
    const int m0 = (j >> 1) * 128;
    const int n0 = (j & 1) * 384;

    const bf16* Ag = P  + (long)batch * 2048 * 2048 + (long)m0 * 2048;
    const bf16* Bg = VT + (long)batch * 768 * 2048  + (long)n0 * 2048;
    const float* Lb = L + (long)batch * 2048;
    const float* Xr = Xres + (long)batch * 2048 * 768;
    float* O = Out + (long)batch * 2048 * 768;

    const int tid = threadIdx.x, wv = tid >> 6, lane = tid & 63;
    const int wr = wv >> 2, wc = wv & 3;      // wave = 64(M) x 96(N)
    const int lr = lane & 15, lq = lane >> 4;

    auto stageA = [&](int slot, int kk, int a) {
        const int lin = a * 64 + lane;
        const int r = lin >> 3;
        const int ck = (lin & 7) ^ (r & 7);
        gload_lds16(Ag + (long)r * 2048 + kk + ck * 8,
                    (char*)lds[slot] + a * 1024);
    };
    auto stageB = [&](int slot, int kk, int b) {
        const int lin = b * 64 + lane;
        const int r = lin >> 3;
        const int ck = (lin & 7) ^ (r & 7);
        gload_lds16(Bg + (long)r * 2048 + kk + ck * 8,
                    (char*)lds[slot] + 16384 + b * 1024);
    };

    v4f acc[4][6] = {};
    const int NT = 32;  // 2048 / 64

    // prologue: stage tile 0 (8 instrs/wave)
    stageA(0, 0, wv * 2 + 0);
    stageA(0, 0, wv * 2 + 1);
    #pragma unroll
    for (int l = 0; l < 6; ++l) stageB(0, 0, wv * 6 + l);
    asm volatile("s_waitcnt vmcnt(0)" ::: "memory");
    __builtin_amdgcn_s_barrier();

    for (int t = 0; t < NT; ++t) {
        const int cur = t & 1, nxt = cur ^ 1;
        const int kk1 = (t + 1) * 64;
        const bf16* As = lds[cur];
        const bf16* Bs = lds[cur] + 8192;     // +16 KB
        const bool pre = (t + 1 < NT);

        // ---- sub-phase 0: A frags + B cols 0..47 (jn 0..2); MFMA 24 ----
        v8bf af[4][2], bfr[3][2];
        #pragma unroll
        for (int i = 0; i < 4; ++i) {
            const int row = wr * 64 + i * 16 + lr;
            #pragma unroll
            for (int s = 0; s < 2; ++s)
                af[i][s] = *(const v8bf*)(As + row * 64 +
                                          (((s * 4 + lq) ^ (row & 7)) << 3));
        }
        #pragma unroll
        for (int jn = 0; jn < 3; ++jn) {
            const int row = wc * 96 + jn * 16 + lr;
            #pragma unroll
            for (int s = 0; s < 2; ++s)
                bfr[jn][s] = *(const v8bf*)(Bs + row * 64 +
                                            (((s * 4 + lq) ^ (row & 7)) << 3));
        }
        if (pre) {
            stageA(nxt, kk1, wv * 2 + 0);
            stageA(nxt, kk1, wv * 2 + 1);
            stageB(nxt, kk1, wv * 6 + 0);
            stageB(nxt, kk1, wv * 6 + 1);
        }
        __builtin_amdgcn_s_barrier();
        asm volatile("s_waitcnt lgkmcnt(0)" ::: "memory");
        __builtin_amdgcn_s_setprio(1);
        #pragma unroll
        for (int s = 0; s < 2; ++s)
            #pragma unroll
            for (int i = 0; i < 4; ++i)
                #pragma unroll
                for (int jn = 0; jn < 3; ++jn)
                    acc[i][jn] = __builtin_amdgcn_mfma_f32_16x16x32_bf16(
                        af[i][s], bfr[jn][s], acc[i][jn], 0, 0, 0);
        __builtin_amdgcn_s_setprio(0);
        __builtin_amdgcn_s_barrier();

        // ---- sub-phase 1: B cols 48..95 (jn 3..5); MFMA 24 ----
        #pragma unroll
        for (int jn = 0; jn < 3; ++jn) {
            const int row = wc * 96 + (jn + 3) * 16 + lr;
            #pragma unroll
            for (int s = 0; s < 2; ++s)
                bfr[jn][s] = *(const v8bf*)(Bs + row * 64 +
                                            (((s * 4 + lq) ^ (row & 7)) << 3));
        }
        if (pre) {
            stageB(nxt, kk1, wv * 6 + 2);
            stageB(nxt, kk1, wv * 6 + 3);
            stageB(nxt, kk1, wv * 6 + 4);
            stageB(nxt, kk1, wv * 6 + 5);
        }
        __builtin_amdgcn_s_barrier();
        asm volatile("s_waitcnt lgkmcnt(0)" ::: "memory");
        __builtin_amdgcn_s_setprio(1);
        #pragma unroll
        for (int s = 0; s < 2; ++s)
            #pragma unroll
            for (int i = 0; i < 4; ++i)
                #pragma unroll
                for (int jn = 0; jn < 3; ++jn)
                    acc[i][jn + 3] = __builtin_amdgcn_mfma_f32_16x16x32_bf16(
                        af[i][s], bfr[jn][s], acc[i][jn + 3], 0, 0, 0);
        __builtin_amdgcn_s_setprio(0);
        if (pre) asm volatile("s_waitcnt vmcnt(0)" ::: "memory");
        __builtin_amdgcn_s_barrier();
    }

    // epilogue: O = acc/L[row] + Xres
    #pragma unroll
    for (int i = 0; i < 4; ++i) {
        #pragma unroll
        for (int rr = 0; rr < 4; ++rr) {
            const int row = m0 + wr * 64 + i * 16 + lq * 4 + rr;
            const float invL = 1.0f / Lb[row];
            #pragma unroll
            for (int jn = 0; jn < 6; ++jn) {
                const int col = n0 + wc * 96 + jn * 16 + lr;
                const long idx = (long)row * 768 + col;
                O[idx] = acc[i][jn][rr] * invL + Xr[idx];
            }
        }
    }
}

// ---------------------------------------------------------------------------
extern "C" void kernel_launch(void* const* d_in, const int* in_sizes, int n_in,
                              void* d_out, int out_size, void* d_ws, size_t ws_size,
                              hipStream_t stream)
{
    const float* x    = (const float*)d_in[0];
    const float* ln_g = (const float*)d_in[1];
    const float* ln_b = (const float*)d_in[2];
    const float* Wq   = (const float*)d_in[3];
    const float* bq   = (const float*)d_in[4];
    const float* Wk   = (const float*)d_in[5];
    const float* bk   = (const float*)d_in[6];
    float* out = (float*)d_out;

    const long R = 8L * 2048;  // 16384 rows
    char* ws = (char*)d_ws;
    size_t off = 0;
    auto take = [&](size_t bytes) -> char* {
        char* p = ws + off;
        off += (bytes + 255) & ~(size_t)255;
        return p;
    };
    bf16*  xn   = (bf16*)take(R * 768 * 2);   // reused as xvT after projection
    bf16*  xv   = (bf16*)take(R * 768 * 2);
    bf16*  Qb   = (bf16*)take(R * 768 * 2);
    bf16*  Kb   = (bf16*)take(R * 768 * 2);
    bf16*  Wcat = (bf16*)take(1536L * 768 * 2);
    float* Lrow = (float*)take(R * 4);        // softmax denominators
    bf16*  Sc   = (bf16*)take(8L * 2048 * 2048 * 2);  // E = exp(scores)

    ln_cast<<<R, 256, 0, stream>>>(x, ln_g, ln_b, xn, xv, Lrow);
    cvt_w<<<dim3(576, 2), 256, 0, stream>>>(Wq, Wk, Wcat);

    const float qscale = 0.036084391824351615f;  // 1/sqrt(768), folded into Q
    gemm_qk<<<1536, 256, 0, stream>>>(xn, Wcat, bq, bk, qscale, Qb, Kb);

    // xn dead now; reuse its buffer for xvT [8][768][2048]
    bf16* xvT = xn;
    transpose_bf<<<dim3(32, 12, 8), 256, 0, stream>>>(xv, xvT);

    gemm_scores<<<1024, 512, 0, stream>>>(Qb, Kb, Sc, Lrow);
    gemm_pv<<<256, 512, 0, stream>>>(Sc, xvT, Lrow, x, out);
}

// Round 3
// 316.287 us; speedup vs baseline: 1.0794x; 1.0615x over previous
//
#include <hip/hip_runtime.h>

typedef __bf16 bf16;
typedef __bf16 v8bf __attribute__((ext_vector_type(8)));
typedef __bf16 v4bf __attribute__((ext_vector_type(4)));
typedef float  v4f  __attribute__((ext_vector_type(4)));

__device__ __forceinline__ void gload_lds16(const void* g, void* l) {
    __builtin_amdgcn_global_load_lds(
        (const __attribute__((address_space(1))) void*)g,
        (__attribute__((address_space(3))) void*)l, 16, 0, 0);
}

#define MFMA16(a, b, c) __builtin_amdgcn_mfma_f32_16x16x32_bf16((a), (b), (c), 0, 0, 0)

// ---------------------------------------------------------------------------
// Kernel 1: LayerNorm over D=768 + bf16 casts. One block per row, 256 thr.
// Blocks 0..63 also zero the softmax row-sum accumulator L (16384 floats).
// ---------------------------------------------------------------------------
__global__ __launch_bounds__(256)
void ln_cast(const float* __restrict__ x, const float* __restrict__ g,
             const float* __restrict__ b, bf16* __restrict__ xn,
             bf16* __restrict__ xv, float* __restrict__ L)
{
    const long row = blockIdx.x;
    const float* xr = x + row * 768;
    const int tid = threadIdx.x;
    const int wave = tid >> 6, lane = tid & 63;

    if (row < 64) L[row * 256 + tid] = 0.0f;

    float a0 = xr[tid], a1 = xr[tid + 256], a2 = xr[tid + 512];
    float s = a0 + a1 + a2;
    #pragma unroll
    for (int off = 32; off; off >>= 1) s += __shfl_xor(s, off);
    __shared__ float sh[4], sh2[4];
    if (!lane) sh[wave] = s;
    __syncthreads();
    const float mu = (sh[0] + sh[1] + sh[2] + sh[3]) * (1.0f / 768.0f);

    float d0 = a0 - mu, d1 = a1 - mu, d2 = a2 - mu;
    float ss = d0 * d0 + d1 * d1 + d2 * d2;
    #pragma unroll
    for (int off = 32; off; off >>= 1) ss += __shfl_xor(ss, off);
    if (!lane) sh2[wave] = ss;
    __syncthreads();
    const float var = (sh2[0] + sh2[1] + sh2[2] + sh2[3]) * (1.0f / 768.0f);
    const float rstd = rsqrtf(var + 1e-5f);

    bf16* xnr = xn + row * 768;
    bf16* xvr = xv + row * 768;
    xnr[tid]       = (bf16)(d0 * rstd * g[tid]       + b[tid]);
    xnr[tid + 256] = (bf16)(d1 * rstd * g[tid + 256] + b[tid + 256]);
    xnr[tid + 512] = (bf16)(d2 * rstd * g[tid + 512] + b[tid + 512]);
    xvr[tid]       = (bf16)a0;
    xvr[tid + 256] = (bf16)a1;
    xvr[tid + 512] = (bf16)a2;
}

// ---------------------------------------------------------------------------
// Kernel 2: weight fp32 -> bf16 convert into Wcat halves. grid (576,2).
// ---------------------------------------------------------------------------
__global__ __launch_bounds__(256)
void cvt_w(const float* __restrict__ Wq, const float* __restrict__ Wk,
           bf16* __restrict__ Wcat)
{
    const int z = blockIdx.y;
    const float* src = z ? Wk : Wq;
    bf16* dst = Wcat + (long)z * 768 * 768;
    const int i = (blockIdx.x * 256 + threadIdx.x) * 4;
    const float4 v = *(const float4*)(src + i);
    v4bf o = {(bf16)v.x, (bf16)v.y, (bf16)v.z, (bf16)v.w};
    *(v4bf*)(dst + i) = o;
}

// ---------------------------------------------------------------------------
// Kernel 2b: 64x64-tile bf16 transpose, XOR-swizzled LDS (conflict-free).
// in: [B][2048][768] -> outT: [B][768][2048]. grid (32, 12, 8), 256 thr.
// ---------------------------------------------------------------------------
__global__ __launch_bounds__(256)
void transpose_bf(const bf16* __restrict__ in, bf16* __restrict__ outT)
{
    __shared__ __attribute__((aligned(16))) bf16 tile[64 * 64];
    const int t0 = blockIdx.x * 64, d0 = blockIdx.y * 64;
    in   += (long)blockIdx.z * 2048 * 768;
    outT += (long)blockIdx.z * 768 * 2048;
    const int tid = threadIdx.x;

    #pragma unroll
    for (int it = 0; it < 2; ++it) {
        const int lin = it * 256 + tid;
        const int r = lin >> 3;
        const int g = lin & 7;
        const int pg = g ^ (r & 7) ^ ((r >> 3) & 7);
        v8bf v = *(const v8bf*)(in + (long)(t0 + r) * 768 + d0 + g * 8);
        *(v8bf*)(tile + r * 64 + pg * 8) = v;
    }
    __syncthreads();
    #pragma unroll
    for (int it = 0; it < 2; ++it) {
        const int lin = it * 256 + tid;
        const int dd = lin >> 3;
        const int tb = lin & 7;
        v8bf o;
        #pragma unroll
        for (int j = 0; j < 8; ++j) {
            const int t = tb * 8 + j;
            const int pg = (dd >> 3) ^ (t & 7) ^ ((t >> 3) & 7);
            o[j] = tile[t * 64 + pg * 8 + (dd & 7)];
        }
        *(v8bf*)(outT + (long)(d0 + dd) * 2048 + t0 + tb * 8) = o;
    }
}

// ---------------------------------------------------------------------------
// Kernel 3: merged Q/K projection. A=xn [16384,768], W=[1536,768] (Wq;Wk).
// 128x128 tile, BK=64 dual-panel m97 staging. grid 1536 1-D, XCD swizzle.
// ---------------------------------------------------------------------------
__global__ __launch_bounds__(256)
void gemm_qk(const bf16* __restrict__ A, const bf16* __restrict__ W,
             const float* __restrict__ bq, const float* __restrict__ bk,
             float qscale, bf16* __restrict__ Qb, bf16* __restrict__ Kb)
{
    __shared__ __attribute__((aligned(16))) bf16 As[2][128 * 32];
    __shared__ __attribute__((aligned(16))) bf16 Bs[2][128 * 32];

    const int bx = blockIdx.x;
    const int r = bx & 7, j = bx >> 3;
    const int m0 = (r * 16 + j / 12) * 128;
    const int n0 = (j % 12) * 128;

    const int tid = threadIdx.x, wave = tid >> 6, lane = tid & 63;
    const bf16* Ab = A + (long)m0 * 768;
    const bf16* Bb = W + (long)n0 * 768;

    const int lrow = lane >> 2;
    const int lk   = (lane & 3) * 8;
    const int wm = (wave >> 1) * 64, wn = (wave & 1) * 64;
    const int lr = lane & 15, lq = lane >> 4;

    v4f acc[4][4] = {};

    for (int kk = 0; kk < 768; kk += 64) {
        #pragma unroll
        for (int p = 0; p < 2; ++p)
            #pragma unroll
            for (int it = 0; it < 2; ++it) {
                const int c = it * 4 + wave;
                const int row = c * 16 + lrow;
                gload_lds16(Ab + (long)row * 768 + kk + p * 32 + lk,
                            (char*)As[p] + c * 1024);
                gload_lds16(Bb + (long)row * 768 + kk + p * 32 + lk,
                            (char*)Bs[p] + c * 1024);
            }
        __syncthreads();

        #pragma unroll
        for (int p = 0; p < 2; ++p) {
            v8bf af[4], bfr[4];
            #pragma unroll
            for (int i = 0; i < 4; ++i)
                af[i] = *(const v8bf*)(As[p] + (wm + i * 16 + lr) * 32 + lq * 8);
            #pragma unroll
            for (int jj = 0; jj < 4; ++jj)
                bfr[jj] = *(const v8bf*)(Bs[p] + (wn + jj * 16 + lr) * 32 + lq * 8);
            #pragma unroll
            for (int i = 0; i < 4; ++i)
                #pragma unroll
                for (int jj = 0; jj < 4; ++jj)
                    acc[i][jj] = MFMA16(af[i], bfr[jj], acc[i][jj]);
        }
        __syncthreads();
    }

    const bool isQ = (n0 < 768);
    const float* bias = isQ ? bq : bk;
    const float sc = isQ ? qscale : 1.0f;
    bf16* C = isQ ? Qb : Kb;
    const int c0 = isQ ? n0 : n0 - 768;

    #pragma unroll
    for (int i = 0; i < 4; ++i) {
        #pragma unroll
        for (int rr = 0; rr < 4; ++rr) {
            const int row = m0 + wm + i * 16 + lq * 4 + rr;
            #pragma unroll
            for (int jj = 0; jj < 4; ++jj) {
                const int col = c0 + wn + jj * 16 + lr;
                C[(long)row * 768 + col] = (bf16)((acc[i][jj][rr] + bias[col]) * sc);
            }
        }
    }
}

// ---------------------------------------------------------------------------
// Kernel 4: E = exp(Q.K^T) + row-sum atomics into L.
// 256x256 tile, 8 waves, wave 128(M)x64(N). K split in half-K-tile H-units
// (A[256][32] 16KB + B[256][32] 16KB = 32KB), ring-4 = 128KB LDS.
// 4 phases/K-tile by (m-half, k-half); each phase: <=8 frag ds_reads
// (read-AHEAD for next phase) + 2 stage chunks + 16 MFMA. Counted vmcnt(2)
// at ph0/ph2 retires exactly the H-unit consumed one phase later.
// XOR chunk swizzle both-sides (64B rows, 4 chunks, ck ^= row&3): balanced
// banks on frag reads, linear gload_lds dest.
// grid 512: batch = bx&7 (XCD), j = bx>>3: mt=j>>3, nt=j&7.
// ---------------------------------------------------------------------------
__global__ __launch_bounds__(512, 2)
void gemm_scores(const bf16* __restrict__ Q, const bf16* __restrict__ K,
                 bf16* __restrict__ E, float* __restrict__ L)
{
    __shared__ __attribute__((aligned(16))) bf16 lds[4][16384];  // 4 x 32 KB

    const int bx = blockIdx.x;
    const int batch = bx & 7, j = bx >> 3;      // j in [0,64)
    const int m0 = (j >> 3) * 256, n0 = (j & 7) * 256;

    const bf16* Ag = Q + (long)batch * 2048 * 768 + (long)m0 * 768;
    const bf16* Bg = K + (long)batch * 2048 * 768 + (long)n0 * 768;
    bf16* C = E + (long)batch * 2048 * 2048;
    float* Lb = L + (long)batch * 2048;

    const int tid = threadIdx.x, wv = tid >> 6, lane = tid & 63;
    const int wr = wv >> 2, wc = wv & 3;        // wave = 128(M) x 64(N)
    const int lr = lane & 15, lq = lane >> 4;

    // stage one 1KB chunk: linear LDS dest, XOR-pre-swizzled global source.
    auto stageA = [&](int h, int a) {
        const int lin = (wv * 2 + a) * 64 + lane;   // A-part: 1024 chunks
        const int r = lin >> 2, pc = lin & 3;
        gload_lds16(Ag + (long)r * 768 + h * 32 + ((pc ^ (r & 3)) << 3),
                    (char*)lds[h & 3] + lin * 16);
    };
    auto stageB = [&](int h, int a) {
        const int lin = (wv * 2 + a) * 64 + lane;
        const int r = lin >> 2, pc = lin & 3;
        gload_lds16(Bg + (long)r * 768 + h * 32 + ((pc ^ (r & 3)) << 3),
                    (char*)lds[h & 3] + 16384 + lin * 16);
    };
    auto rdA = [&](int h, int mf) -> v8bf {
        const int r = wr * 128 + mf * 16 + lr;
        return *(const v8bf*)(lds[h & 3] + r * 32 + ((lq ^ (r & 3)) << 3));
    };
    auto rdB = [&](int h, int nf) -> v8bf {
        const int r = wc * 64 + nf * 16 + lr;
        return *(const v8bf*)(lds[h & 3] + 8192 + r * 32 + ((lq ^ (r & 3)) << 3));
    };

    v8bf a0[4], a1[4], b0[4], b1[4];
    v4f acc[8][4] = {};
    const int NT = 12;  // 768/64

    // prologue: stage H0,H1 (8 chunks/wave); retire H0; read phase-0 frags.
    stageA(0, 0); stageA(0, 1); stageB(0, 0); stageB(0, 1);
    stageA(1, 0); stageA(1, 1); stageB(1, 0); stageB(1, 1);
    asm volatile("s_waitcnt vmcnt(4)" ::: "memory");
    __builtin_amdgcn_s_barrier();
    #pragma unroll
    for (int i = 0; i < 4; ++i) a0[i] = rdA(0, i);
    #pragma unroll
    for (int jn = 0; jn < 4; ++jn) b0[jn] = rdB(0, jn);

    for (int t = 0; t < NT; ++t) {
        const int h0 = 2 * t, h1 = 2 * t + 1, h2 = 2 * t + 2, h3 = 2 * t + 3;
        const bool pre = (t + 1 < NT);

        // ph0: read A(h0) m4-7 (for ph1); stage h2.A; MFMA m0-3 x s0
        #pragma unroll
        for (int i = 0; i < 4; ++i) a1[i] = rdA(h0, 4 + i);
        if (pre) { stageA(h2, 0); stageA(h2, 1); }
        __builtin_amdgcn_s_setprio(1);
        #pragma unroll
        for (int i = 0; i < 4; ++i)
            #pragma unroll
            for (int jn = 0; jn < 4; ++jn)
                acc[i][jn] = MFMA16(a0[i], b0[jn], acc[i][jn]);
        __builtin_amdgcn_s_setprio(0);
        asm volatile("s_waitcnt vmcnt(2)" ::: "memory");   // H(h1) landed
        __builtin_amdgcn_s_barrier();

        // ph1: read A(h1) m0-3 + B(h1) (for ph2); stage h2.B; MFMA m4-7 x s0
        #pragma unroll
        for (int i = 0; i < 4; ++i) a0[i] = rdA(h1, i);
        #pragma unroll
        for (int jn = 0; jn < 4; ++jn) b1[jn] = rdB(h1, jn);
        if (pre) { stageB(h2, 0); stageB(h2, 1); }
        __builtin_amdgcn_s_setprio(1);
        #pragma unroll
        for (int i = 0; i < 4; ++i)
            #pragma unroll
            for (int jn = 0; jn < 4; ++jn)
                acc[4 + i][jn] = MFMA16(a1[i], b0[jn], acc[4 + i][jn]);
        __builtin_amdgcn_s_setprio(0);
        asm volatile("" ::: "memory");
        __builtin_amdgcn_s_barrier();

        // ph2: read A(h1) m4-7 (for ph3); stage h3.A; MFMA m0-3 x s1
        #pragma unroll
        for (int i = 0; i < 4; ++i) a1[i] = rdA(h1, 4 + i);
        if (pre) { stageA(h3, 0); stageA(h3, 1); }
        __builtin_amdgcn_s_setprio(1);
        #pragma unroll
        for (int i = 0; i < 4; ++i)
            #pragma unroll
            for (int jn = 0; jn < 4; ++jn)
                acc[i][jn] = MFMA16(a0[i], b1[jn], acc[i][jn]);
        __builtin_amdgcn_s_setprio(0);
        asm volatile("s_waitcnt vmcnt(2)" ::: "memory");   // H(h2) landed
        __builtin_amdgcn_s_barrier();

        // ph3: read A(h2) m0-3 + B(h2) (for next ph0); stage h3.B; MFMA m4-7 x s1
        if (pre) {
            #pragma unroll
            for (int i = 0; i < 4; ++i) a0[i] = rdA(h2, i);
            #pragma unroll
            for (int jn = 0; jn < 4; ++jn) b0[jn] = rdB(h2, jn);
            stageB(h3, 0); stageB(h3, 1);
        }
        __builtin_amdgcn_s_setprio(1);
        #pragma unroll
        for (int i = 0; i < 4; ++i)
            #pragma unroll
            for (int jn = 0; jn < 4; ++jn)
                acc[4 + i][jn] = MFMA16(a1[i], b1[jn], acc[4 + i][jn]);
        __builtin_amdgcn_s_setprio(0);
        asm volatile("" ::: "memory");
        __builtin_amdgcn_s_barrier();
    }

    // epilogue: exp + 16-lane row-sum reduce + atomics + bf16 store
    #pragma unroll
    for (int i = 0; i < 8; ++i) {
        #pragma unroll
        for (int rr = 0; rr < 4; ++rr) {
            const int row = m0 + wr * 128 + i * 16 + lq * 4 + rr;
            float e[4], rs = 0.f;
            #pragma unroll
            for (int jn = 0; jn < 4; ++jn) {
                e[jn] = __expf(acc[i][jn][rr]);
                rs += e[jn];
            }
            #pragma unroll
            for (int off = 1; off < 16; off <<= 1) rs += __shfl_xor(rs, off);
            if (lr == 0) atomicAdd(&Lb[row], rs);
            #pragma unroll
            for (int jn = 0; jn < 4; ++jn) {
                const int col = n0 + wc * 64 + jn * 16 + lr;
                C[(long)row * 2048 + col] = (bf16)e[jn];
            }
        }
    }
}

// ---------------------------------------------------------------------------
// Kernel 5: Out = (E.V^T)/L + Xres. 128(M)x384(N) tile, 8 waves, wave 64x96.
// Same 4-H-unit ring pipeline as gemm_scores: H = A[128][32] 8KB +
// B[384][32] 24KB = 32KB, ring-4 = 128KB. Phases by (k-half, n-half):
// per-phase reads 7/3/7/3 vs 12 MFMA, read-ahead + counted vmcnt(2).
// grid 256 = 1 block/CU: batch = bx&7, j = bx>>3: mt=j>>1, nt=j&1.
// ---------------------------------------------------------------------------
__global__ __launch_bounds__(512, 2)
void gemm_pv(const bf16* __restrict__ P, const bf16* __restrict__ VT,
             const float* __restrict__ L, const float* __restrict__ Xres,
             float* __restrict__ Out)
{
    __shared__ __attribute__((aligned(16))) bf16 lds[4][16384];  // 4 x 32 KB

    const int bx = blockIdx.x;
    const int batch = bx & 7, j = bx >> 3;   // j in [0,32)
    const int m0 = (j >> 1) * 128;
    const int n0 = (j & 1) * 384;

    const bf16* Ag = P  + (long)batch * 2048 * 2048 + (long)m0 * 2048;
    const bf16* Bg = VT + (long)batch * 768 * 2048  + (long)n0 * 2048;
    const float* Lb = L + (long)batch * 2048;
    const float* Xr = Xres + (long)batch * 2048 * 768;
    float* O = Out + (long)batch * 2048 * 768;

    const int tid = threadIdx.x, wv = tid >> 6, lane = tid & 63;
    const int wr = wv >> 2, wc = wv & 3;      // wave = 64(M) x 96(N)
    const int lr = lane & 15, lq = lane >> 4;

    auto stageA = [&](int h) {                // 8 chunks: 1 per wave
        const int lin = wv * 64 + lane;
        const int r = lin >> 2, pc = lin & 3;
        gload_lds16(Ag + (long)r * 2048 + h * 32 + ((pc ^ (r & 3)) << 3),
                    (char*)lds[h & 3] + lin * 16);
    };
    auto stageB = [&](int h, int a) {         // 24 chunks: 3 per wave
        const int lin = (wv * 3 + a) * 64 + lane;
        const int r = lin >> 2, pc = lin & 3;
        gload_lds16(Bg + (long)r * 2048 + h * 32 + ((pc ^ (r & 3)) << 3),
                    (char*)lds[h & 3] + 8192 + lin * 16);
    };
    auto rdA = [&](int h, int mf) -> v8bf {
        const int r = wr * 64 + mf * 16 + lr;
        return *(const v8bf*)(lds[h & 3] + r * 32 + ((lq ^ (r & 3)) << 3));
    };
    auto rdB = [&](int h, int nf) -> v8bf {
        const int r = wc * 96 + nf * 16 + lr;
        return *(const v8bf*)(lds[h & 3] + 4096 + r * 32 + ((lq ^ (r & 3)) << 3));
    };

    v8bf a0[4], a1[4], bL[3], bH[3];
    v4f acc[4][6] = {};
    const int NT = 32;  // 2048/64

    // prologue
    stageA(0); stageB(0, 0); stageB(0, 1); stageB(0, 2);
    stageA(1); stageB(1, 0); stageB(1, 1); stageB(1, 2);
    asm volatile("s_waitcnt vmcnt(4)" ::: "memory");
    __builtin_amdgcn_s_barrier();
    #pragma unroll
    for (int i = 0; i < 4; ++i) a0[i] = rdA(0, i);
    #pragma unroll
    for (int jn = 0; jn < 3; ++jn) bL[jn] = rdB(0, jn);

    for (int t = 0; t < NT; ++t) {
        const int h0 = 2 * t, h1 = 2 * t + 1, h2 = 2 * t + 2, h3 = 2 * t + 3;
        const bool pre = (t + 1 < NT);

        // ph0: read B(h0) n3-5; stage h2.A + h2.B0; MFMA a0 x bL (s0 lo)
        #pragma unroll
        for (int jn = 0; jn < 3; ++jn) bH[jn] = rdB(h0, 3 + jn);
        if (pre) { stageA(h2); stageB(h2, 0); }
        __builtin_amdgcn_s_setprio(1);
        #pragma unroll
        for (int i = 0; i < 4; ++i)
            #pragma unroll
            for (int jn = 0; jn < 3; ++jn)
                acc[i][jn] = MFMA16(a0[i], bL[jn], acc[i][jn]);
        __builtin_amdgcn_s_setprio(0);
        asm volatile("s_waitcnt vmcnt(2)" ::: "memory");   // H(h1) landed
        __builtin_amdgcn_s_barrier();

        // ph1: read A(h1) + B(h1) n0-2; stage h2.B1 + h2.B2; MFMA a0 x bH (s0 hi)
        #pragma unroll
        for (int i = 0; i < 4; ++i) a1[i] = rdA(h1, i);
        #pragma unroll
        for (int jn = 0; jn < 3; ++jn) bL[jn] = rdB(h1, jn);
        if (pre) { stageB(h2, 1); stageB(h2, 2); }
        __builtin_amdgcn_s_setprio(1);
        #pragma unroll
        for (int i = 0; i < 4; ++i)
            #pragma unroll
            for (int jn = 0; jn < 3; ++jn)
                acc[i][3 + jn] = MFMA16(a0[i], bH[jn], acc[i][3 + jn]);
        __builtin_amdgcn_s_setprio(0);
        asm volatile("" ::: "memory");
        __builtin_amdgcn_s_barrier();

        // ph2: read B(h1) n3-5; stage h3.A + h3.B0; MFMA a1 x bL (s1 lo)
        #pragma unroll
        for (int jn = 0; jn < 3; ++jn) bH[jn] = rdB(h1, 3 + jn);
        if (pre) { stageA(h3); stageB(h3, 0); }
        __builtin_amdgcn_s_setprio(1);
        #pragma unroll
        for (int i = 0; i < 4; ++i)
            #pragma unroll
            for (int jn = 0; jn < 3; ++jn)
                acc[i][jn] = MFMA16(a1[i], bL[jn], acc[i][jn]);
        __builtin_amdgcn_s_setprio(0);
        asm volatile("s_waitcnt vmcnt(2)" ::: "memory");   // H(h2) landed
        __builtin_amdgcn_s_barrier();

        // ph3: read A(h2) + B(h2) n0-2 (for next ph0); stage h3.B1+B2; MFMA a1 x bH
        if (pre) {
            #pragma unroll
            for (int i = 0; i < 4; ++i) a0[i] = rdA(h2, i);
            #pragma unroll
            for (int jn = 0; jn < 3; ++jn) bL[jn] = rdB(h2, jn);
            stageB(h3, 1); stageB(h3, 2);
        }
        __builtin_amdgcn_s_setprio(1);
        #pragma unroll
        for (int i = 0; i < 4; ++i)
            #pragma unroll
            for (int jn = 0; jn < 3; ++jn)
                acc[i][3 + jn] = MFMA16(a1[i], bH[jn], acc[i][3 + jn]);
        __builtin_amdgcn_s_setprio(0);
        asm volatile("" ::: "memory");
        __builtin_amdgcn_s_barrier();
    }

    // epilogue: O = acc/L[row] + Xres
    #pragma unroll
    for (int i = 0; i < 4; ++i) {
        #pragma unroll
        for (int rr = 0; rr < 4; ++rr) {
            const int row = m0 + wr * 64 + i * 16 + lq * 4 + rr;
            const float invL = 1.0f / Lb[row];
            #pragma unroll
            for (int jn = 0; jn < 6; ++jn) {
                const int col = n0 + wc * 96 + jn * 16 + lr;
                const long idx = (long)row * 768 + col;
                O[idx] = acc[i][jn][rr] * invL + Xr[idx];
            }
        }
    }
}

// ---------------------------------------------------------------------------
extern "C" void kernel_launch(void* const* d_in, const int* in_sizes, int n_in,
                              void* d_out, int out_size, void* d_ws, size_t ws_size,
                              hipStream_t stream)
{
    const float* x    = (const float*)d_in[0];
    const float* ln_g = (const float*)d_in[1];
    const float* ln_b = (const float*)d_in[2];
    const float* Wq   = (const float*)d_in[3];
    const float* bq   = (const float*)d_in[4];
    const float* Wk   = (const float*)d_in[5];
    const float* bk   = (const float*)d_in[6];
    float* out = (float*)d_out;

    const long R = 8L * 2048;  // 16384 rows
    char* ws = (char*)d_ws;
    size_t off = 0;
    auto take = [&](size_t bytes) -> char* {
        char* p = ws + off;
        off += (bytes + 255) & ~(size_t)255;
        return p;
    };
    bf16*  xn   = (bf16*)take(R * 768 * 2);   // reused as xvT after projection
    bf16*  xv   = (bf16*)take(R * 768 * 2);
    bf16*  Qb   = (bf16*)take(R * 768 * 2);
    bf16*  Kb   = (bf16*)take(R * 768 * 2);
    bf16*  Wcat = (bf16*)take(1536L * 768 * 2);
    float* Lrow = (float*)take(R * 4);        // softmax denominators
    bf16*  Sc   = (bf16*)take(8L * 2048 * 2048 * 2);  // E = exp(scores)

    ln_cast<<<R, 256, 0, stream>>>(x, ln_g, ln_b, xn, xv, Lrow);
    cvt_w<<<dim3(576, 2), 256, 0, stream>>>(Wq, Wk, Wcat);

    const float qscale = 0.036084391824351615f;  // 1/sqrt(768), folded into Q
    gemm_qk<<<1536, 256, 0, stream>>>(xn, Wcat, bq, bk, qscale, Qb, Kb);

    // xn dead now; reuse its buffer for xvT [8][768][2048]
    bf16* xvT = xn;
    transpose_bf<<<dim3(32, 12, 8), 256, 0, stream>>>(xv, xvT);

    gemm_scores<<<512, 512, 0, stream>>>(Qb, Kb, Sc, Lrow);
    gemm_pv<<<256, 512, 0, stream>>>(Sc, xvT, Lrow, x, out);
}

// Round 4
// 312.114 us; speedup vs baseline: 1.0938x; 1.0134x over previous
//
#include <hip/hip_runtime.h>

typedef __bf16 bf16;
typedef __bf16 v8bf __attribute__((ext_vector_type(8)));
typedef __bf16 v4bf __attribute__((ext_vector_type(4)));
typedef float  v4f  __attribute__((ext_vector_type(4)));

__device__ __forceinline__ void gload_lds16(const void* g, void* l) {
    __builtin_amdgcn_global_load_lds(
        (const __attribute__((address_space(1))) void*)g,
        (__attribute__((address_space(3))) void*)l, 16, 0, 0);
}

#define MFMA16(a, b, c) __builtin_amdgcn_mfma_f32_16x16x32_bf16((a), (b), (c), 0, 0, 0)

// ---------------------------------------------------------------------------
// Kernel 1: LayerNorm over D=768 + bf16 casts. One block per row, 256 thr.
// Blocks 0..63 also zero the softmax row-sum accumulator L (16384 floats).
// ---------------------------------------------------------------------------
__global__ __launch_bounds__(256)
void ln_cast(const float* __restrict__ x, const float* __restrict__ g,
             const float* __restrict__ b, bf16* __restrict__ xn,
             bf16* __restrict__ xv, float* __restrict__ L)
{
    const long row = blockIdx.x;
    const float* xr = x + row * 768;
    const int tid = threadIdx.x;
    const int wave = tid >> 6, lane = tid & 63;

    if (row < 64) L[row * 256 + tid] = 0.0f;

    float a0 = xr[tid], a1 = xr[tid + 256], a2 = xr[tid + 512];
    float s = a0 + a1 + a2;
    #pragma unroll
    for (int off = 32; off; off >>= 1) s += __shfl_xor(s, off);
    __shared__ float sh[4], sh2[4];
    if (!lane) sh[wave] = s;
    __syncthreads();
    const float mu = (sh[0] + sh[1] + sh[2] + sh[3]) * (1.0f / 768.0f);

    float d0 = a0 - mu, d1 = a1 - mu, d2 = a2 - mu;
    float ss = d0 * d0 + d1 * d1 + d2 * d2;
    #pragma unroll
    for (int off = 32; off; off >>= 1) ss += __shfl_xor(ss, off);
    if (!lane) sh2[wave] = ss;
    __syncthreads();
    const float var = (sh2[0] + sh2[1] + sh2[2] + sh2[3]) * (1.0f / 768.0f);
    const float rstd = rsqrtf(var + 1e-5f);

    bf16* xnr = xn + row * 768;
    bf16* xvr = xv + row * 768;
    xnr[tid]       = (bf16)(d0 * rstd * g[tid]       + b[tid]);
    xnr[tid + 256] = (bf16)(d1 * rstd * g[tid + 256] + b[tid + 256]);
    xnr[tid + 512] = (bf16)(d2 * rstd * g[tid + 512] + b[tid + 512]);
    xvr[tid]       = (bf16)a0;
    xvr[tid + 256] = (bf16)a1;
    xvr[tid + 512] = (bf16)a2;
}

// ---------------------------------------------------------------------------
// Kernel 2: weight fp32 -> bf16 convert into Wcat halves. grid (576,2).
// ---------------------------------------------------------------------------
__global__ __launch_bounds__(256)
void cvt_w(const float* __restrict__ Wq, const float* __restrict__ Wk,
           bf16* __restrict__ Wcat)
{
    const int z = blockIdx.y;
    const float* src = z ? Wk : Wq;
    bf16* dst = Wcat + (long)z * 768 * 768;
    const int i = (blockIdx.x * 256 + threadIdx.x) * 4;
    const float4 v = *(const float4*)(src + i);
    v4bf o = {(bf16)v.x, (bf16)v.y, (bf16)v.z, (bf16)v.w};
    *(v4bf*)(dst + i) = o;
}

// ---------------------------------------------------------------------------
// Kernel 2b: 64x64-tile bf16 transpose, XOR-swizzled LDS (conflict-free).
// in: [B][2048][768] -> outT: [B][768][2048]. grid (32, 12, 8), 256 thr.
// ---------------------------------------------------------------------------
__global__ __launch_bounds__(256)
void transpose_bf(const bf16* __restrict__ in, bf16* __restrict__ outT)
{
    __shared__ __attribute__((aligned(16))) bf16 tile[64 * 64];
    const int t0 = blockIdx.x * 64, d0 = blockIdx.y * 64;
    in   += (long)blockIdx.z * 2048 * 768;
    outT += (long)blockIdx.z * 768 * 2048;
    const int tid = threadIdx.x;

    #pragma unroll
    for (int it = 0; it < 2; ++it) {
        const int lin = it * 256 + tid;
        const int r = lin >> 3;
        const int g = lin & 7;
        const int pg = g ^ (r & 7) ^ ((r >> 3) & 7);
        v8bf v = *(const v8bf*)(in + (long)(t0 + r) * 768 + d0 + g * 8);
        *(v8bf*)(tile + r * 64 + pg * 8) = v;
    }
    __syncthreads();
    #pragma unroll
    for (int it = 0; it < 2; ++it) {
        const int lin = it * 256 + tid;
        const int dd = lin >> 3;
        const int tb = lin & 7;
        v8bf o;
        #pragma unroll
        for (int j = 0; j < 8; ++j) {
            const int t = tb * 8 + j;
            const int pg = (dd >> 3) ^ (t & 7) ^ ((t >> 3) & 7);
            o[j] = tile[t * 64 + pg * 8 + (dd & 7)];
        }
        *(v8bf*)(outT + (long)(d0 + dd) * 2048 + t0 + tb * 8) = o;
    }
}

// ---------------------------------------------------------------------------
// Kernel 3: merged Q/K projection. A=xn [16384,768], W=[1536,768] (Wq;Wk).
// 128x128 tile, BK=64 dual-panel m97 staging. grid 1536 1-D, XCD swizzle.
// ---------------------------------------------------------------------------
__global__ __launch_bounds__(256)
void gemm_qk(const bf16* __restrict__ A, const bf16* __restrict__ W,
             const float* __restrict__ bq, const float* __restrict__ bk,
             float qscale, bf16* __restrict__ Qb, bf16* __restrict__ Kb)
{
    __shared__ __attribute__((aligned(16))) bf16 As[2][128 * 32];
    __shared__ __attribute__((aligned(16))) bf16 Bs[2][128 * 32];

    const int bx = blockIdx.x;
    const int r = bx & 7, j = bx >> 3;
    const int m0 = (r * 16 + j / 12) * 128;
    const int n0 = (j % 12) * 128;

    const int tid = threadIdx.x, wave = tid >> 6, lane = tid & 63;
    const bf16* Ab = A + (long)m0 * 768;
    const bf16* Bb = W + (long)n0 * 768;

    const int lrow = lane >> 2;
    const int lk   = (lane & 3) * 8;
    const int wm = (wave >> 1) * 64, wn = (wave & 1) * 64;
    const int lr = lane & 15, lq = lane >> 4;

    v4f acc[4][4] = {};

    for (int kk = 0; kk < 768; kk += 64) {
        #pragma unroll
        for (int p = 0; p < 2; ++p)
            #pragma unroll
            for (int it = 0; it < 2; ++it) {
                const int c = it * 4 + wave;
                const int row = c * 16 + lrow;
                gload_lds16(Ab + (long)row * 768 + kk + p * 32 + lk,
                            (char*)As[p] + c * 1024);
                gload_lds16(Bb + (long)row * 768 + kk + p * 32 + lk,
                            (char*)Bs[p] + c * 1024);
            }
        __syncthreads();

        #pragma unroll
        for (int p = 0; p < 2; ++p) {
            v8bf af[4], bfr[4];
            #pragma unroll
            for (int i = 0; i < 4; ++i)
                af[i] = *(const v8bf*)(As[p] + (wm + i * 16 + lr) * 32 + lq * 8);
            #pragma unroll
            for (int jj = 0; jj < 4; ++jj)
                bfr[jj] = *(const v8bf*)(Bs[p] + (wn + jj * 16 + lr) * 32 + lq * 8);
            #pragma unroll
            for (int i = 0; i < 4; ++i)
                #pragma unroll
                for (int jj = 0; jj < 4; ++jj)
                    acc[i][jj] = MFMA16(af[i], bfr[jj], acc[i][jj]);
        }
        __syncthreads();
    }

    const bool isQ = (n0 < 768);
    const float* bias = isQ ? bq : bk;
    const float sc = isQ ? qscale : 1.0f;
    bf16* C = isQ ? Qb : Kb;
    const int c0 = isQ ? n0 : n0 - 768;

    #pragma unroll
    for (int i = 0; i < 4; ++i) {
        #pragma unroll
        for (int rr = 0; rr < 4; ++rr) {
            const int row = m0 + wm + i * 16 + lq * 4 + rr;
            #pragma unroll
            for (int jj = 0; jj < 4; ++jj) {
                const int col = c0 + wn + jj * 16 + lr;
                C[(long)row * 768 + col] = (bf16)((acc[i][jj][rr] + bias[col]) * sc);
            }
        }
    }
}

// ---------------------------------------------------------------------------
// Kernel 4: E = exp(Q.K^T) + row-sum atomics into L.
// m201-faithful port: 256x256 tile, BK=64 (128-B rows, 8-chunk XOR swizzle =
// proven zero-conflict), double-buffer (2 x 64 KB), 4 phases/K-tile in gray
// quadrant order (m0n0, m1n0, m1n1, m0n1). Each phase: {ds_read this phase's
// frags + stage 1 half-tile + barrier + setprio/16 MFMA + counted vmcnt +
// barrier}. Wave layout interleaved (row = mh*128 + wr*64, col = nh*128 +
// wc*32) so each phase touches exactly one A and one B half-tile.
// Stage order A-lo,B-lo,A-hi,B-hi matches first-read order; per-wave ledger
// gives vmcnt(4) at ph0/ph1/ph3 (none at ph2), 4-8 loads always in flight,
// no drain in the main loop. Tail: clamped re-stage keeps loop uniform.
// grid 512: batch = bx&7 (XCD), j = bx>>3: mt=j>>3, nt=j&7.
// ---------------------------------------------------------------------------
__global__ __launch_bounds__(512, 2)
void gemm_scores(const bf16* __restrict__ Q, const bf16* __restrict__ K,
                 bf16* __restrict__ E, float* __restrict__ L)
{
    __shared__ __attribute__((aligned(16))) bf16 lds[2][32768];  // 2 x 64 KB

    const int bx = blockIdx.x;
    const int batch = bx & 7, j = bx >> 3;      // j in [0,64)
    const int m0 = (j >> 3) * 256, n0 = (j & 7) * 256;

    const bf16* Ag = Q + (long)batch * 2048 * 768 + (long)m0 * 768;
    const bf16* Bg = K + (long)batch * 2048 * 768 + (long)n0 * 768;
    bf16* C = E + (long)batch * 2048 * 2048;
    float* Lb = L + (long)batch * 2048;

    const int tid = threadIdx.x, wv = tid >> 6, lane = tid & 63;
    const int wr = wv >> 2, wc = wv & 3;
    const int lr = lane & 15, lq = lane >> 4;

    // stage 1 KB chunk: linear LDS dest, XOR-pre-swizzled global source.
    auto stA = [&](int bi, int h, int p, int kk) {
        const int lin = (wv * 2 + p) * 64 + lane;        // 0..1023 -> 16 KB
        const int r = lin >> 3, ck = (lin & 7) ^ (r & 7);
        gload_lds16(Ag + (long)(h * 128 + r) * 768 + kk + ck * 8,
                    (char*)lds + bi * 65536 + h * 16384 + lin * 16);
    };
    auto stB = [&](int bi, int h, int p, int kk) {
        const int lin = (wv * 2 + p) * 64 + lane;
        const int r = lin >> 3, ck = (lin & 7) ^ (r & 7);
        gload_lds16(Bg + (long)(h * 128 + r) * 768 + kk + ck * 8,
                    (char*)lds + bi * 65536 + 32768 + h * 16384 + lin * 16);
    };

    v8bf a[4][2], b[2][2];
    v4f acc[2][2][4][2] = {};   // [mh][nh][i][n]

    auto rdA = [&](const bf16* Ls, int mh) {
        #pragma unroll
        for (int i = 0; i < 4; ++i) {
            const int r = mh * 128 + wr * 64 + i * 16 + lr;
            #pragma unroll
            for (int s = 0; s < 2; ++s)
                a[i][s] = *(const v8bf*)(Ls + r * 64 + (((s * 4 + lq) ^ (r & 7)) << 3));
        }
    };
    auto rdB = [&](const bf16* Ls, int nh) {
        #pragma unroll
        for (int n = 0; n < 2; ++n) {
            const int r = nh * 128 + wc * 32 + n * 16 + lr;
            #pragma unroll
            for (int s = 0; s < 2; ++s)
                b[n][s] = *(const v8bf*)(Ls + 16384 + r * 64 + (((s * 4 + lq) ^ (r & 7)) << 3));
        }
    };
    auto mm = [&](v4f (&ac)[4][2]) {
        __builtin_amdgcn_s_setprio(1);
        #pragma unroll
        for (int s = 0; s < 2; ++s)
            #pragma unroll
            for (int i = 0; i < 4; ++i)
                #pragma unroll
                for (int n = 0; n < 2; ++n)
                    ac[i][n] = MFMA16(a[i][s], b[n][s], ac[i][n]);
        __builtin_amdgcn_s_setprio(0);
    };

    const int NT = 12;  // 768/64
    // prologue: buffer0 <- K-tile 0, order A-lo, B-lo, A-hi, B-hi
    stA(0, 0, 0, 0); stA(0, 0, 1, 0); stB(0, 0, 0, 0); stB(0, 0, 1, 0);
    stA(0, 1, 0, 0); stA(0, 1, 1, 0); stB(0, 1, 0, 0); stB(0, 1, 1, 0);
    asm volatile("s_waitcnt vmcnt(4)" ::: "memory");   // A-lo,B-lo landed
    __builtin_amdgcn_s_barrier();

    for (int t = 0; t < NT; ++t) {
        const int cur = t & 1, nxt = cur ^ 1;
        const int kk2 = (t + 1 < NT ? t + 1 : NT - 1) * 64;
        const bf16* Ls = lds[cur];

        // ph0 (m0,n0): reads A-lo,B-lo; stages nxt.A-lo
        rdA(Ls, 0); rdB(Ls, 0);
        stA(nxt, 0, 0, kk2); stA(nxt, 0, 1, kk2);
        __builtin_amdgcn_s_barrier();
        mm(acc[0][0]);
        asm volatile("s_waitcnt vmcnt(4)" ::: "memory");   // cur.A-hi landed
        __builtin_amdgcn_s_barrier();

        // ph1 (m1,n0): reads A-hi; stages nxt.B-lo
        rdA(Ls, 1);
        stB(nxt, 0, 0, kk2); stB(nxt, 0, 1, kk2);
        __builtin_amdgcn_s_barrier();
        mm(acc[1][0]);
        asm volatile("s_waitcnt vmcnt(4)" ::: "memory");   // cur.B-hi landed
        __builtin_amdgcn_s_barrier();

        // ph2 (m1,n1): reads B-hi; stages nxt.A-hi  (no vmcnt needed)
        rdB(Ls, 1);
        stA(nxt, 1, 0, kk2); stA(nxt, 1, 1, kk2);
        __builtin_amdgcn_s_barrier();
        mm(acc[1][1]);
        __builtin_amdgcn_s_barrier();

        // ph3 (m0,n1): reads A-lo (landed); stages nxt.B-hi
        rdA(Ls, 0);
        stB(nxt, 1, 0, kk2); stB(nxt, 1, 1, kk2);
        __builtin_amdgcn_s_barrier();
        mm(acc[0][1]);
        asm volatile("s_waitcnt vmcnt(4)" ::: "memory");   // nxt.A-lo,B-lo landed
        __builtin_amdgcn_s_barrier();
    }
    asm volatile("s_waitcnt vmcnt(0)" ::: "memory");       // drain tail re-stage

    // epilogue: exp + 16-lane row-sum reduce + atomics + bf16 store
    #pragma unroll
    for (int mh = 0; mh < 2; ++mh)
    #pragma unroll
    for (int i = 0; i < 4; ++i) {
        #pragma unroll
        for (int rr = 0; rr < 4; ++rr) {
            const int row = m0 + mh * 128 + wr * 64 + i * 16 + lq * 4 + rr;
            float e[4], rs = 0.f;
            #pragma unroll
            for (int nh = 0; nh < 2; ++nh)
                #pragma unroll
                for (int n = 0; n < 2; ++n) {
                    e[nh * 2 + n] = __expf(acc[mh][nh][i][n][rr]);
                    rs += e[nh * 2 + n];
                }
            #pragma unroll
            for (int off = 1; off < 16; off <<= 1) rs += __shfl_xor(rs, off);
            if (lr == 0) atomicAdd(&Lb[row], rs);
            #pragma unroll
            for (int nh = 0; nh < 2; ++nh)
                #pragma unroll
                for (int n = 0; n < 2; ++n) {
                    const int col = n0 + nh * 128 + wc * 32 + n * 16 + lr;
                    C[(long)row * 2048 + col] = (bf16)e[nh * 2 + n];
                }
        }
    }
}

// ---------------------------------------------------------------------------
// Kernel 5: Out = (E.V^T)/L + Xres. Same m201-style structure as gemm_scores:
// 128(M)x384(N) tile, BK=64, double-buffer 2x64KB, 4 gray phases/K-tile.
// Wave 64x96 interleaved: row = mh*64 + wr*32, col = nh*192 + wc*48.
// Half-tiles: A-lo/A-hi = 1 load/wave, B-lo/B-hi = 3 loads/wave. Stage order
// {A-lo,B-lo0}{B-lo1,B-lo2}{A-hi,B-hi0}{B-hi1,B-hi2}; ledger: vmcnt(5) ph0,
// vmcnt(4) ph1, none ph2, vmcnt(4) ph3. grid 256 = 1 block/CU, batch=bx&7.
// ---------------------------------------------------------------------------
__global__ __launch_bounds__(512, 2)
void gemm_pv(const bf16* __restrict__ P, const bf16* __restrict__ VT,
             const float* __restrict__ L, const float* __restrict__ Xres,
             float* __restrict__ Out)
{
    __shared__ __attribute__((aligned(16))) bf16 lds[2][32768];  // 2 x 64 KB

    const int bx = blockIdx.x;
    const int batch = bx & 7, j = bx >> 3;   // j in [0,32)
    const int m0 = (j >> 1) * 128;
    const int n0 = (j & 1) * 384;

    const bf16* Ag = P  + (long)batch * 2048 * 2048 + (long)m0 * 2048;
    const bf16* Bg = VT + (long)batch * 768 * 2048  + (long)n0 * 2048;
    const float* Lb = L + (long)batch * 2048;
    const float* Xr = Xres + (long)batch * 2048 * 768;
    float* O = Out + (long)batch * 2048 * 768;

    const int tid = threadIdx.x, wv = tid >> 6, lane = tid & 63;
    const int wr = wv >> 2, wc = wv & 3;
    const int lr = lane & 15, lq = lane >> 4;

    auto stA = [&](int bi, int h, int kk) {            // 1 load/wave = 8 KB
        const int lin = wv * 64 + lane;                // 0..511
        const int r = lin >> 3, ck = (lin & 7) ^ (r & 7);
        gload_lds16(Ag + (long)(h * 64 + r) * 2048 + kk + ck * 8,
                    (char*)lds + bi * 65536 + h * 8192 + lin * 16);
    };
    auto stB = [&](int bi, int h, int p, int kk) {     // 3 loads/wave = 24 KB
        const int lin = (wv * 3 + p) * 64 + lane;      // 0..1535
        const int r = lin >> 3, ck = (lin & 7) ^ (r & 7);
        gload_lds16(Bg + (long)(h * 192 + r) * 2048 + kk + ck * 8,
                    (char*)lds + bi * 65536 + 16384 + h * 24576 + lin * 16);
    };

    v8bf a[2][2], b[3][2];
    v4f acc[2][2][2][3] = {};   // [mh][nh][i][n]

    auto rdA = [&](const bf16* Ls, int mh) {
        #pragma unroll
        for (int i = 0; i < 2; ++i) {
            const int r = mh * 64 + wr * 32 + i * 16 + lr;
            #pragma unroll
            for (int s = 0; s < 2; ++s)
                a[i][s] = *(const v8bf*)(Ls + r * 64 + (((s * 4 + lq) ^ (r & 7)) << 3));
        }
    };
    auto rdB = [&](const bf16* Ls, int nh) {
        #pragma unroll
        for (int n = 0; n < 3; ++n) {
            const int r = nh * 192 + wc * 48 + n * 16 + lr;
            #pragma unroll
            for (int s = 0; s < 2; ++s)
                b[n][s] = *(const v8bf*)(Ls + 8192 + r * 64 + (((s * 4 + lq) ^ (r & 7)) << 3));
        }
    };
    auto mm = [&](v4f (&ac)[2][3]) {
        __builtin_amdgcn_s_setprio(1);
        #pragma unroll
        for (int s = 0; s < 2; ++s)
            #pragma unroll
            for (int i = 0; i < 2; ++i)
                #pragma unroll
                for (int n = 0; n < 3; ++n)
                    ac[i][n] = MFMA16(a[i][s], b[n][s], ac[i][n]);
        __builtin_amdgcn_s_setprio(0);
    };

    const int NT = 32;  // 2048/64
    // prologue: buffer0, order A-lo, B-lo0..2, A-hi, B-hi0..2
    stA(0, 0, 0); stB(0, 0, 0, 0); stB(0, 0, 1, 0); stB(0, 0, 2, 0);
    stA(0, 1, 0); stB(0, 1, 0, 0); stB(0, 1, 1, 0); stB(0, 1, 2, 0);
    asm volatile("s_waitcnt vmcnt(4)" ::: "memory");   // A-lo + B-lo landed
    __builtin_amdgcn_s_barrier();

    for (int t = 0; t < NT; ++t) {
        const int cur = t & 1, nxt = cur ^ 1;
        const int kk2 = (t + 1 < NT ? t + 1 : NT - 1) * 64;
        const bf16* Ls = lds[cur];

        // ph0 (m0,n0)
        rdA(Ls, 0); rdB(Ls, 0);
        stA(nxt, 0, kk2); stB(nxt, 0, 0, kk2);
        __builtin_amdgcn_s_barrier();
        mm(acc[0][0]);
        asm volatile("s_waitcnt vmcnt(5)" ::: "memory");   // cur.A-hi landed
        __builtin_amdgcn_s_barrier();

        // ph1 (m1,n0)
        rdA(Ls, 1);
        stB(nxt, 0, 1, kk2); stB(nxt, 0, 2, kk2);
        __builtin_amdgcn_s_barrier();
        mm(acc[1][0]);
        asm volatile("s_waitcnt vmcnt(4)" ::: "memory");   // cur.B-hi landed
        __builtin_amdgcn_s_barrier();

        // ph2 (m1,n1)  (no vmcnt needed)
        rdB(Ls, 1);
        stA(nxt, 1, kk2); stB(nxt, 1, 0, kk2);
        __builtin_amdgcn_s_barrier();
        mm(acc[1][1]);
        __builtin_amdgcn_s_barrier();

        // ph3 (m0,n1)
        rdA(Ls, 0);
        stB(nxt, 1, 1, kk2); stB(nxt, 1, 2, kk2);
        __builtin_amdgcn_s_barrier();
        mm(acc[0][1]);
        asm volatile("s_waitcnt vmcnt(4)" ::: "memory");   // nxt.A-lo,B-lo landed
        __builtin_amdgcn_s_barrier();
    }
    asm volatile("s_waitcnt vmcnt(0)" ::: "memory");

    // epilogue: O = acc/L[row] + Xres
    #pragma unroll
    for (int mh = 0; mh < 2; ++mh)
    #pragma unroll
    for (int i = 0; i < 2; ++i) {
        #pragma unroll
        for (int rr = 0; rr < 4; ++rr) {
            const int row = m0 + mh * 64 + wr * 32 + i * 16 + lq * 4 + rr;
            const float invL = 1.0f / Lb[row];
            #pragma unroll
            for (int nh = 0; nh < 2; ++nh)
                #pragma unroll
                for (int n = 0; n < 3; ++n) {
                    const int col = n0 + nh * 192 + wc * 48 + n * 16 + lr;
                    const long idx = (long)row * 768 + col;
                    O[idx] = acc[mh][nh][i][n][rr] * invL + Xr[idx];
                }
        }
    }
}

// ---------------------------------------------------------------------------
extern "C" void kernel_launch(void* const* d_in, const int* in_sizes, int n_in,
                              void* d_out, int out_size, void* d_ws, size_t ws_size,
                              hipStream_t stream)
{
    const float* x    = (const float*)d_in[0];
    const float* ln_g = (const float*)d_in[1];
    const float* ln_b = (const float*)d_in[2];
    const float* Wq   = (const float*)d_in[3];
    const float* bq   = (const float*)d_in[4];
    const float* Wk   = (const float*)d_in[5];
    const float* bk   = (const float*)d_in[6];
    float* out = (float*)d_out;

    const long R = 8L * 2048;  // 16384 rows
    char* ws = (char*)d_ws;
    size_t off = 0;
    auto take = [&](size_t bytes) -> char* {
        char* p = ws + off;
        off += (bytes + 255) & ~(size_t)255;
        return p;
    };
    bf16*  xn   = (bf16*)take(R * 768 * 2);   // reused as xvT after projection
    bf16*  xv   = (bf16*)take(R * 768 * 2);
    bf16*  Qb   = (bf16*)take(R * 768 * 2);
    bf16*  Kb   = (bf16*)take(R * 768 * 2);
    bf16*  Wcat = (bf16*)take(1536L * 768 * 2);
    float* Lrow = (float*)take(R * 4);        // softmax denominators
    bf16*  Sc   = (bf16*)take(8L * 2048 * 2048 * 2);  // E = exp(scores)

    ln_cast<<<R, 256, 0, stream>>>(x, ln_g, ln_b, xn, xv, Lrow);
    cvt_w<<<dim3(576, 2), 256, 0, stream>>>(Wq, Wk, Wcat);

    const float qscale = 0.036084391824351615f;  // 1/sqrt(768), folded into Q
    gemm_qk<<<1536, 256, 0, stream>>>(xn, Wcat, bq, bk, qscale, Qb, Kb);

    // xn dead now; reuse its buffer for xvT [8][768][2048]
    bf16* xvT = xn;
    transpose_bf<<<dim3(32, 12, 8), 256, 0, stream>>>(xv, xvT);

    gemm_scores<<<512, 512, 0, stream>>>(Qb, Kb, Sc, Lrow);
    gemm_pv<<<256, 512, 0, stream>>>(Sc, xvT, Lrow, x, out);
}